// Round 2
// baseline (608.791 us; speedup 1.0000x reference)
//
#include <hip/hip_runtime.h>
#include <math.h>

#define B 8
#define S 128
#define E 192
#define H 6
#define HD 32
#define L 64
#define NEXP 8
#define ED 768
#define T (B*S)     // 1024
#define SE (S*E)    // 24576
#define LE (L*E)    // 12288

#define SPLITS 96
#define ISPAN 256   // 24576/96
#define CHUNK 128

// ---------------- RMSNorm (one wave per row of 192) ----------------
__global__ __launch_bounds__(64) void rmsnorm_k(const float* __restrict__ x,
                                                const float* __restrict__ w,
                                                float* __restrict__ y) {
  int row = blockIdx.x;
  int lane = threadIdx.x;
  const float* xr = x + (size_t)row * E;
  float v0 = xr[lane], v1 = xr[lane + 64], v2 = xr[lane + 128];
  float s = v0 * v0 + v1 * v1 + v2 * v2;
#pragma unroll
  for (int off = 32; off > 0; off >>= 1) s += __shfl_xor(s, off);
  float inv = rsqrtf(s * (1.0f / E) + 1e-5f);
  float* yr = y + (size_t)row * E;
  yr[lane]       = v0 * inv * w[lane];
  yr[lane + 64]  = v1 * inv * w[lane + 64];
  yr[lane + 128] = v2 * inv * w[lane + 128];
}

// ---------------- latent GEMM: partials over i-splits ----------------
// latent[b][j] = sum_i xn[b][i] * latW[i][j]   (i<24576, j<12288, b<8)
// grid: (12 j-blocks of 1024, SPLITS), block 256; thread owns 4 consecutive j.
__global__ __launch_bounds__(256) void lat_partial_k(const float* __restrict__ xn,
                                                     const float* __restrict__ latW,
                                                     float* __restrict__ part) {
  const int tid = threadIdx.x;
  const int j = blockIdx.x * 1024 + tid * 4;
  const int i0 = blockIdx.y * ISPAN;
  __shared__ float4 xs[CHUNK][2];
  float4 acc[8];
#pragma unroll
  for (int b = 0; b < 8; ++b) acc[b] = make_float4(0.f, 0.f, 0.f, 0.f);
  for (int c = 0; c < ISPAN; c += CHUNK) {
    float* xsf = (float*)xs;
    __syncthreads();
    for (int l = tid; l < CHUNK * 8; l += 256) {
      int ii = l >> 3, b = l & 7;
      xsf[l] = xn[(size_t)b * SE + i0 + c + ii];
    }
    __syncthreads();
#pragma unroll 4
    for (int ii = 0; ii < CHUNK; ++ii) {
      const float4 w = *(const float4*)&latW[(size_t)(i0 + c + ii) * LE + j];
      const float4 xa = xs[ii][0];
      const float4 xb = xs[ii][1];
#define FMA4(xv, a) acc[a].x += (xv) * w.x; acc[a].y += (xv) * w.y; \
                    acc[a].z += (xv) * w.z; acc[a].w += (xv) * w.w;
      FMA4(xa.x, 0) FMA4(xa.y, 1) FMA4(xa.z, 2) FMA4(xa.w, 3)
      FMA4(xb.x, 4) FMA4(xb.y, 5) FMA4(xb.z, 6) FMA4(xb.w, 7)
#undef FMA4
    }
  }
#pragma unroll
  for (int b = 0; b < 8; ++b)
    *(float4*)&part[((size_t)blockIdx.y * 8 + b) * LE + j] = acc[b];
}

__global__ __launch_bounds__(256) void lat_reduce_k(const float* __restrict__ part,
                                                    const float* __restrict__ latb,
                                                    float* __restrict__ lat) {
  int g = blockIdx.x * 256 + threadIdx.x;  // < 8*LE
  int b = g / LE, j = g - b * LE;
  float s = latb[j];
  for (int sp = 0; sp < SPLITS; ++sp) s += part[((size_t)sp * 8 + b) * LE + j];
  lat[g] = s;
}

// ---------------- generic fp32 GEMM: C = act(A@W + bias) (+resid) ----------------
// 64x64 tile, BK=16, 256 threads, 4x4 per-thread micro-tile. M%64==0, N%64==0, K%16==0.
__global__ __launch_bounds__(256) void gemm_k(const float* __restrict__ A,
                                              const float* __restrict__ W,
                                              const float* __restrict__ bias,
                                              const float* __restrict__ resid,
                                              float* __restrict__ C,
                                              int M, int N, int K,
                                              long aB, long wB, long bB, long cB,
                                              int flags) {
  const int n0 = blockIdx.x * 64;
  const int m0 = blockIdx.y * 64;
  const int e = blockIdx.z;
  A += (size_t)e * aB;
  W += (size_t)e * wB;
  C += (size_t)e * cB;
  const float* bp = bias ? bias + (size_t)e * bB : nullptr;
  __shared__ float As[16][64];
  __shared__ float Ws[16][64];
  const int tid = threadIdx.x;
  const int tx = tid & 15, ty = tid >> 4;
  const int arow = tid >> 2, acol = (tid & 3) << 2;
  const int wrow = tid >> 4, wcol = (tid & 15) << 2;
  float acc[4][4] = {{0.f}};
  for (int kb = 0; kb < K; kb += 16) {
    float4 a = *(const float4*)&A[(size_t)(m0 + arow) * K + kb + acol];
    As[acol][arow] = a.x;
    As[acol + 1][arow] = a.y;
    As[acol + 2][arow] = a.z;
    As[acol + 3][arow] = a.w;
    *(float4*)&Ws[wrow][wcol] = *(const float4*)&W[(size_t)(kb + wrow) * N + n0 + wcol];
    __syncthreads();
#pragma unroll
    for (int k = 0; k < 16; ++k) {
      float4 a4 = *(const float4*)&As[k][ty << 2];
      float4 w4 = *(const float4*)&Ws[k][tx << 2];
      acc[0][0] += a4.x * w4.x; acc[0][1] += a4.x * w4.y; acc[0][2] += a4.x * w4.z; acc[0][3] += a4.x * w4.w;
      acc[1][0] += a4.y * w4.x; acc[1][1] += a4.y * w4.y; acc[1][2] += a4.y * w4.z; acc[1][3] += a4.y * w4.w;
      acc[2][0] += a4.z * w4.x; acc[2][1] += a4.z * w4.y; acc[2][2] += a4.z * w4.z; acc[2][3] += a4.z * w4.w;
      acc[3][0] += a4.w * w4.x; acc[3][1] += a4.w * w4.y; acc[3][2] += a4.w * w4.z; acc[3][3] += a4.w * w4.w;
    }
    __syncthreads();
  }
#pragma unroll
  for (int i = 0; i < 4; ++i) {
    int m = m0 + (ty << 2) + i;
#pragma unroll
    for (int j = 0; j < 4; ++j) {
      int n = n0 + (tx << 2) + j;
      float v = acc[i][j];
      if (bp) v += bp[n];
      if (flags & 1) v = fmaxf(v, 0.f);
      if (flags & 2) v += resid[(size_t)m * N + n];
      C[(size_t)m * N + n] = v;
    }
  }
}

// ---------------- RoPE on q (interleaved pairs), query only ----------------
__global__ __launch_bounds__(256) void rope_k(float* __restrict__ q) {
  int gid = blockIdx.x * 256 + threadIdx.x;  // T*H*16 = 98304
  int d = gid & 15;
  int h = (gid >> 4) % H;
  int t = gid / (16 * H);
  int s = t & (S - 1);
  float invf = exp2f(-(float)d * (1.0f / 16.0f) * log2f(10000.0f));
  float ang = (float)s * invf;
  float sn, cs;
  sincosf(ang, &sn, &cs);
  float2* p = (float2*)&q[(size_t)t * E + h * HD + 2 * d];
  float2 v = *p;
  *p = make_float2(v.x * cs - v.y * sn, v.x * sn + v.y * cs);
}

// ---------------- attention: one block per (b,h), thread = query row ----------------
__global__ __launch_bounds__(128) void attn_k(const float* __restrict__ q,
                                              const float* __restrict__ kk,
                                              const float* __restrict__ vv,
                                              float* __restrict__ ao) {
  int b = blockIdx.x / H, h = blockIdx.x % H;
  __shared__ float ks[64][32], vs[64][32];
  int tid = threadIdx.x;
  {
    int l = tid >> 1, hf = (tid & 1) * 16;
    const float4* ksrc = (const float4*)&kk[(size_t)(b * L + l) * E + h * HD + hf];
    const float4* vsrc = (const float4*)&vv[(size_t)(b * L + l) * E + h * HD + hf];
    float4* kdst = (float4*)&ks[l][hf];
    float4* vdst = (float4*)&vs[l][hf];
#pragma unroll
    for (int u = 0; u < 4; ++u) { kdst[u] = ksrc[u]; vdst[u] = vsrc[u]; }
  }
  __syncthreads();
  int s = tid;
  const float* qp = &q[(size_t)(b * S + s) * E + h * HD];
  float qv[32];
#pragma unroll
  for (int d = 0; d < 32; ++d) qv[d] = qp[d];
  const float scale = 0.17677669529663687f;  // 1/sqrt(32)
  float mx = -1e30f;
  for (int l = 0; l < 64; ++l) {
    float dot = 0.f;
#pragma unroll
    for (int d = 0; d < 32; ++d) dot += qv[d] * ks[l][d];
    mx = fmaxf(mx, dot * scale);
  }
  float o[32];
#pragma unroll
  for (int d = 0; d < 32; ++d) o[d] = 0.f;
  float sum = 0.f;
  for (int l = 0; l < 64; ++l) {
    float dot = 0.f;
#pragma unroll
    for (int d = 0; d < 32; ++d) dot += qv[d] * ks[l][d];
    float wgt = __expf(dot * scale - mx);
    sum += wgt;
#pragma unroll
    for (int d = 0; d < 32; ++d) o[d] += wgt * vs[l][d];
  }
  float inv = 1.0f / sum;
  float* op = &ao[(size_t)(b * S + s) * E + h * HD];
#pragma unroll
  for (int d = 0; d < 32; ++d) op[d] = o[d] * inv;
}

// ---------------- router: softmax over 8 + top2 (lowest-index tie-break) ----------------
__global__ __launch_bounds__(64) void router_k(const float* __restrict__ hbuf,
                                               const float* __restrict__ rW,
                                               const float* __restrict__ rb,
                                               float* __restrict__ pk,
                                               int* __restrict__ idx) {
  int t = blockIdx.x * 64 + threadIdx.x;
  float lg[8];
#pragma unroll
  for (int n = 0; n < 8; ++n) lg[n] = rb[n];
  const float* hp = &hbuf[(size_t)t * E];
  for (int e2 = 0; e2 < E; ++e2) {
    float hv = hp[e2];
    const float* wr = &rW[e2 * 8];
#pragma unroll
    for (int n = 0; n < 8; ++n) lg[n] += hv * wr[n];
  }
  float mx = lg[0];
#pragma unroll
  for (int n = 1; n < 8; ++n) mx = fmaxf(mx, lg[n]);
  float p[8], sum = 0.f;
#pragma unroll
  for (int n = 0; n < 8; ++n) { p[n] = __expf(lg[n] - mx); sum += p[n]; }
  float inv = 1.f / sum;
#pragma unroll
  for (int n = 0; n < 8; ++n) p[n] *= inv;
  int i0 = 0;
#pragma unroll
  for (int n = 1; n < 8; ++n) if (p[n] > p[i0]) i0 = n;
  int i1 = (i0 == 0) ? 1 : 0;
#pragma unroll
  for (int n = 0; n < 8; ++n) if (n != i0 && p[n] > p[i1]) i1 = n;
  pk[t * 2] = p[i0];
  pk[t * 2 + 1] = p[i1];
  idx[t * 2] = i0;
  idx[t * 2 + 1] = i1;
}

// ---------------- combine: out = x1 + pk0*eo[i0] + pk1*eo[i1] ----------------
__global__ __launch_bounds__(256) void combine_k(const float* __restrict__ x1,
                                                 const float* __restrict__ eo,
                                                 const float* __restrict__ pk,
                                                 const int* __restrict__ idx,
                                                 float* __restrict__ out) {
  int g = blockIdx.x * 256 + threadIdx.x;  // T*E = 196608
  int t = g / E;
  int e = g - t * E;
  int i0 = idx[t * 2], i1 = idx[t * 2 + 1];
  out[g] = x1[g] + pk[t * 2] * eo[((size_t)i0 * T + t) * E + e]
                 + pk[t * 2 + 1] * eo[((size_t)i1 * T + t) * E + e];
}

extern "C" void kernel_launch(void* const* d_in, const int* in_sizes, int n_in,
                              void* d_out, int out_size, void* d_ws, size_t ws_size,
                              hipStream_t stream) {
  const float* x    = (const float*)d_in[0];
  const float* r1w  = (const float*)d_in[1];
  const float* r2w  = (const float*)d_in[2];
  const float* latW = (const float*)d_in[3];
  const float* latb = (const float*)d_in[4];
  const float* qW   = (const float*)d_in[5];
  const float* qb   = (const float*)d_in[6];
  const float* kW   = (const float*)d_in[7];
  const float* kb   = (const float*)d_in[8];
  const float* vW   = (const float*)d_in[9];
  const float* vb   = (const float*)d_in[10];
  const float* oW   = (const float*)d_in[11];
  const float* ob   = (const float*)d_in[12];
  const float* rW   = (const float*)d_in[13];
  const float* rb   = (const float*)d_in[14];
  const float* e1W  = (const float*)d_in[15];
  const float* e1b  = (const float*)d_in[16];
  const float* swW  = (const float*)d_in[17];
  const float* swb  = (const float*)d_in[18];
  const float* e2W  = (const float*)d_in[19];
  const float* e2b  = (const float*)d_in[20];
  float* out = (float*)d_out;

  float* ws = (float*)d_ws;
  float* xn1  = ws;                 // 196608
  float* lat  = ws + 196608;        // 98304
  float* qbuf = ws + 294912;        // 196608
  float* kbuf = ws + 491520;        // 98304
  float* vbuf = ws + 589824;        // 98304
  float* ao   = ws + 688128;        // 196608
  float* x1   = ws + 884736;        // 196608
  float* hbuf = ws + 1081344;       // 196608
  float* pk   = ws + 1277952;       // 2048
  int*   idx  = (int*)(ws + 1280000);  // 2048 ints
  float* big  = ws + 1282048;
  float* part = big;                      // 96*98304 = 9437184
  float* t1   = big;                      // 6291456 (after reduce, part dead)
  float* t2   = big + 6291456;            // 6291456
  float* eo   = big + 12582912;           // 1572864

  // 1) rmsnorm1
  rmsnorm_k<<<T, 64, 0, stream>>>(x, r1w, xn1);
  // 2) latent = xn1 @ latW + latb
  lat_partial_k<<<dim3(12, SPLITS), 256, 0, stream>>>(xn1, latW, part);
  lat_reduce_k<<<(8 * LE) / 256, 256, 0, stream>>>(part, latb, lat);
  // 3) q,k,v projections
  gemm_k<<<dim3(3, 16, 1), 256, 0, stream>>>(xn1, qW, qb, nullptr, qbuf, T, E, E, 0, 0, 0, 0, 0);
  gemm_k<<<dim3(3, 8, 1), 256, 0, stream>>>(lat, kW, kb, nullptr, kbuf, B * L, E, E, 0, 0, 0, 0, 0);
  gemm_k<<<dim3(3, 8, 1), 256, 0, stream>>>(lat, vW, vb, nullptr, vbuf, B * L, E, E, 0, 0, 0, 0, 0);
  // 4) rope on q
  rope_k<<<(T * H * 16) / 256, 256, 0, stream>>>(qbuf);
  // 5) attention
  attn_k<<<B * H, 128, 0, stream>>>(qbuf, kbuf, vbuf, ao);
  // 6) o-proj + residual
  gemm_k<<<dim3(3, 16, 1), 256, 0, stream>>>(ao, oW, ob, x, x1, T, E, E, 0, 0, 0, 0, 2);
  // 7) rmsnorm2
  rmsnorm_k<<<T, 64, 0, stream>>>(x1, r2w, hbuf);
  // 8) router
  router_k<<<T / 64, 64, 0, stream>>>(hbuf, rW, rb, pk, idx);
  // 9) MoE dense stages
  gemm_k<<<dim3(12, 16, NEXP), 256, 0, stream>>>(hbuf, e1W, e1b, nullptr, t1,
      T, ED, E, 0, (long)E * ED, ED, (long)T * ED, 0);
  gemm_k<<<dim3(12, 16, NEXP), 256, 0, stream>>>(t1, swW, swb, nullptr, t2,
      T, ED, ED, (long)T * ED, (long)ED * ED, ED, (long)T * ED, 1);
  gemm_k<<<dim3(3, 16, NEXP), 256, 0, stream>>>(t2, e2W, e2b, nullptr, eo,
      T, E, ED, (long)T * ED, (long)ED * E, E, (long)T * E, 0);
  // 10) combine
  combine_k<<<(T * E) / 256, 256, 0, stream>>>(x1, eo, pk, idx, out);
}

// Round 4
// 441.341 us; speedup vs baseline: 1.3794x; 1.3794x over previous
//
#include <hip/hip_runtime.h>
#include <hip/hip_bf16.h>
#include <math.h>

#define B 8
#define S 128
#define E 192
#define H 6
#define HD 32
#define L 64
#define NEXP 8
#define ED 768
#define T (B*S)     // 1024
#define SE (S*E)    // 24576
#define LE (L*E)    // 12288

#define SPLITS 96
#define ISPAN 256   // 24576/96
#define CHUNK 128

using s8 = __attribute__((ext_vector_type(8))) short;   // 8 bf16 (4 VGPRs)
using f4 = __attribute__((ext_vector_type(4))) float;   // 4 fp32 acc

// ---------------- RMSNorm (one wave per row of 192) ----------------
__global__ __launch_bounds__(64) void rmsnorm_k(const float* __restrict__ x,
                                                const float* __restrict__ w,
                                                float* __restrict__ y) {
  int row = blockIdx.x;
  int lane = threadIdx.x;
  const float* xr = x + (size_t)row * E;
  float v0 = xr[lane], v1 = xr[lane + 64], v2 = xr[lane + 128];
  float s = v0 * v0 + v1 * v1 + v2 * v2;
#pragma unroll
  for (int off = 32; off > 0; off >>= 1) s += __shfl_xor(s, off);
  float inv = rsqrtf(s * (1.0f / E) + 1e-5f);
  float* yr = y + (size_t)row * E;
  yr[lane]       = v0 * inv * w[lane];
  yr[lane + 64]  = v1 * inv * w[lane + 64];
  yr[lane + 128] = v2 * inv * w[lane + 128];
}

// RMSNorm writing fp32 AND bf16 outputs
__global__ __launch_bounds__(64) void rmsnorm_bf_k(const float* __restrict__ x,
                                                   const float* __restrict__ w,
                                                   float* __restrict__ y,
                                                   __hip_bfloat16* __restrict__ yb) {
  int row = blockIdx.x;
  int lane = threadIdx.x;
  const float* xr = x + (size_t)row * E;
  float v0 = xr[lane], v1 = xr[lane + 64], v2 = xr[lane + 128];
  float s = v0 * v0 + v1 * v1 + v2 * v2;
#pragma unroll
  for (int off = 32; off > 0; off >>= 1) s += __shfl_xor(s, off);
  float inv = rsqrtf(s * (1.0f / E) + 1e-5f);
  float r0 = v0 * inv * w[lane];
  float r1 = v1 * inv * w[lane + 64];
  float r2 = v2 * inv * w[lane + 128];
  float* yr = y + (size_t)row * E;
  __hip_bfloat16* yrb = yb + (size_t)row * E;
  yr[lane] = r0; yr[lane + 64] = r1; yr[lane + 128] = r2;
  yrb[lane] = __float2bfloat16(r0);
  yrb[lane + 64] = __float2bfloat16(r1);
  yrb[lane + 128] = __float2bfloat16(r2);
}

// ---------------- latent GEMM: partials over i-splits ----------------
__global__ __launch_bounds__(256) void lat_partial_k(const float* __restrict__ xn,
                                                     const float* __restrict__ latW,
                                                     float* __restrict__ part) {
  const int tid = threadIdx.x;
  const int j = blockIdx.x * 1024 + tid * 4;
  const int i0 = blockIdx.y * ISPAN;
  __shared__ float4 xs[CHUNK][2];
  float4 acc[8];
#pragma unroll
  for (int b = 0; b < 8; ++b) acc[b] = make_float4(0.f, 0.f, 0.f, 0.f);
  for (int c = 0; c < ISPAN; c += CHUNK) {
    float* xsf = (float*)xs;
    __syncthreads();
    for (int l = tid; l < CHUNK * 8; l += 256) {
      int ii = l >> 3, b = l & 7;
      xsf[l] = xn[(size_t)b * SE + i0 + c + ii];
    }
    __syncthreads();
#pragma unroll 4
    for (int ii = 0; ii < CHUNK; ++ii) {
      const float4 w = *(const float4*)&latW[(size_t)(i0 + c + ii) * LE + j];
      const float4 xa = xs[ii][0];
      const float4 xb = xs[ii][1];
#define FMA4(xv, a) acc[a].x += (xv) * w.x; acc[a].y += (xv) * w.y; \
                    acc[a].z += (xv) * w.z; acc[a].w += (xv) * w.w;
      FMA4(xa.x, 0) FMA4(xa.y, 1) FMA4(xa.z, 2) FMA4(xa.w, 3)
      FMA4(xb.x, 4) FMA4(xb.y, 5) FMA4(xb.z, 6) FMA4(xb.w, 7)
#undef FMA4
    }
  }
#pragma unroll
  for (int b = 0; b < 8; ++b)
    *(float4*)&part[((size_t)blockIdx.y * 8 + b) * LE + j] = acc[b];
}

__global__ __launch_bounds__(256) void lat_reduce_k(const float* __restrict__ part,
                                                    const float* __restrict__ latb,
                                                    float* __restrict__ lat) {
  int g = blockIdx.x * 256 + threadIdx.x;  // < 8*LE
  int b = g / LE, j = g - b * LE;
  float s = latb[j];
  for (int sp = 0; sp < SPLITS; ++sp) s += part[((size_t)sp * 8 + b) * LE + j];
  lat[g] = s;
}

// ---------------- generic fp32 GEMM (small projections) ----------------
__global__ __launch_bounds__(256) void gemm_k(const float* __restrict__ A,
                                              const float* __restrict__ W,
                                              const float* __restrict__ bias,
                                              const float* __restrict__ resid,
                                              float* __restrict__ C,
                                              int M, int N, int K,
                                              long aB, long wB, long bB, long cB,
                                              int flags) {
  const int n0 = blockIdx.x * 64;
  const int m0 = blockIdx.y * 64;
  const int e = blockIdx.z;
  A += (size_t)e * aB;
  W += (size_t)e * wB;
  C += (size_t)e * cB;
  const float* bp = bias ? bias + (size_t)e * bB : nullptr;
  __shared__ float As[16][64];
  __shared__ float Ws[16][64];
  const int tid = threadIdx.x;
  const int tx = tid & 15, ty = tid >> 4;
  const int arow = tid >> 2, acol = (tid & 3) << 2;
  const int wrow = tid >> 4, wcol = (tid & 15) << 2;
  float acc[4][4] = {{0.f}};
  for (int kb = 0; kb < K; kb += 16) {
    float4 a = *(const float4*)&A[(size_t)(m0 + arow) * K + kb + acol];
    As[acol][arow] = a.x;
    As[acol + 1][arow] = a.y;
    As[acol + 2][arow] = a.z;
    As[acol + 3][arow] = a.w;
    *(float4*)&Ws[wrow][wcol] = *(const float4*)&W[(size_t)(kb + wrow) * N + n0 + wcol];
    __syncthreads();
#pragma unroll
    for (int k = 0; k < 16; ++k) {
      float4 a4 = *(const float4*)&As[k][ty << 2];
      float4 w4 = *(const float4*)&Ws[k][tx << 2];
      acc[0][0] += a4.x * w4.x; acc[0][1] += a4.x * w4.y; acc[0][2] += a4.x * w4.z; acc[0][3] += a4.x * w4.w;
      acc[1][0] += a4.y * w4.x; acc[1][1] += a4.y * w4.y; acc[1][2] += a4.y * w4.z; acc[1][3] += a4.y * w4.w;
      acc[2][0] += a4.z * w4.x; acc[2][1] += a4.z * w4.y; acc[2][2] += a4.z * w4.z; acc[2][3] += a4.z * w4.w;
      acc[3][0] += a4.w * w4.x; acc[3][1] += a4.w * w4.y; acc[3][2] += a4.w * w4.z; acc[3][3] += a4.w * w4.w;
    }
    __syncthreads();
  }
#pragma unroll
  for (int i = 0; i < 4; ++i) {
    int m = m0 + (ty << 2) + i;
#pragma unroll
    for (int j = 0; j < 4; ++j) {
      int n = n0 + (tx << 2) + j;
      float v = acc[i][j];
      if (bp) v += bp[n];
      if (flags & 1) v = fmaxf(v, 0.f);
      if (flags & 2) v += resid[(size_t)m * N + n];
      C[(size_t)m * N + n] = v;
    }
  }
}

// ---------------- weight transpose + fp32->bf16: out[n][k] = in[k][n] ----------------
__global__ __launch_bounds__(256) void tconv_k(const float* __restrict__ in,
                                               __hip_bfloat16* __restrict__ out,
                                               int K, int N) {
  const int e = blockIdx.z;
  in += (size_t)e * K * N;
  out += (size_t)e * N * K;
  __shared__ float tile[32][33];
  int tx = threadIdx.x & 31, r8 = threadIdx.x >> 5;
  int k0 = blockIdx.x * 32, n0 = blockIdx.y * 32;
#pragma unroll
  for (int i = 0; i < 4; ++i)
    tile[r8 + 8 * i][tx] = in[(size_t)(k0 + r8 + 8 * i) * N + n0 + tx];
  __syncthreads();
#pragma unroll
  for (int i = 0; i < 4; ++i) {
    int nr = r8 + 8 * i;
    out[(size_t)(n0 + nr) * K + k0 + tx] = __float2bfloat16(tile[tx][nr]);
  }
}

// ---------------- bf16 MFMA GEMM: C = act(A @ Wt^T + bias) ----------------
// A: [M][K] bf16 row-major; Wt: [N][K] bf16 (pre-transposed); per-expert strides in elems.
// Tile 128x64, BK=64, 256 threads = 4 waves (2m x 2n), wave tile 64x32 = 4x2 frags 16x16.
// flags: 1 = relu, 2 = fp32 output (else bf16 output).
__global__ __launch_bounds__(256) void moe_gemm_k(const __hip_bfloat16* __restrict__ A_,
                                                  const __hip_bfloat16* __restrict__ Wt_,
                                                  const float* __restrict__ bias_,
                                                  void* __restrict__ C_,
                                                  int M, int N, int K,
                                                  long aB, long wB, long bB, long cB,
                                                  int flags) {
  const int e = blockIdx.z;
  const short* A = (const short*)A_ + (size_t)e * aB;
  const short* Wt = (const short*)Wt_ + (size_t)e * wB;
  const float* bias = bias_ + (size_t)e * bB;
  const int n0 = blockIdx.x * 64;
  const int m0 = blockIdx.y * 128;
  __shared__ short As[128 * 64];  // 16 KB, XOR-swizzled 16B slots
  __shared__ short Bs[64 * 64];   // 8 KB
  const int tid = threadIdx.x;
  const int lane = tid & 63, wid = tid >> 6;
  const int wr = wid >> 1, wc = wid & 1;
  const int lr = lane & 15, lg = lane >> 4;
  f4 acc[4][2];
#pragma unroll
  for (int fm = 0; fm < 4; ++fm)
#pragma unroll
    for (int fn = 0; fn < 2; ++fn) acc[fm][fn] = (f4){0.f, 0.f, 0.f, 0.f};

  for (int kb = 0; kb < K; kb += 64) {
    __syncthreads();
#pragma unroll
    for (int p = 0; p < 4; ++p) {   // stage A: 128 rows x 64 bf16
      int eidx = p * 256 + tid;
      int row = eidx >> 3, slot = eidx & 7;
      s8 v = *(const s8*)(A + (size_t)(m0 + row) * K + kb + slot * 8);
      *(s8*)&As[row * 64 + ((slot ^ (row & 7)) << 3)] = v;
    }
#pragma unroll
    for (int p = 0; p < 2; ++p) {   // stage B: 64 rows x 64 bf16
      int eidx = p * 256 + tid;
      int row = eidx >> 3, slot = eidx & 7;
      s8 v = *(const s8*)(Wt + (size_t)(n0 + row) * K + kb + slot * 8);
      *(s8*)&Bs[row * 64 + ((slot ^ (row & 7)) << 3)] = v;
    }
    __syncthreads();
#pragma unroll
    for (int kk = 0; kk < 64; kk += 32) {
      const int sb = (kk >> 3) + lg;  // 16B slot index of this lane's k-group
      s8 af[4], bf[2];
#pragma unroll
      for (int fm = 0; fm < 4; ++fm) {
        int row = wr * 64 + fm * 16 + lr;
        af[fm] = *(const s8*)&As[row * 64 + ((sb ^ (row & 7)) << 3)];
      }
#pragma unroll
      for (int fn = 0; fn < 2; ++fn) {
        int row = wc * 32 + fn * 16 + lr;
        bf[fn] = *(const s8*)&Bs[row * 64 + ((sb ^ (row & 7)) << 3)];
      }
#pragma unroll
      for (int fm = 0; fm < 4; ++fm)
#pragma unroll
        for (int fn = 0; fn < 2; ++fn)
          acc[fm][fn] = __builtin_amdgcn_mfma_f32_16x16x32_bf16(af[fm], bf[fn], acc[fm][fn], 0, 0, 0);
    }
  }
  // epilogue: C/D layout col=lane&15, row=(lane>>4)*4+j (measured m89/m91)
#pragma unroll
  for (int fm = 0; fm < 4; ++fm) {
#pragma unroll
    for (int fn = 0; fn < 2; ++fn) {
      int col = n0 + wc * 32 + fn * 16 + lr;
      int rowb = m0 + wr * 64 + fm * 16 + lg * 4;
      float bv = bias[col];
#pragma unroll
      for (int j = 0; j < 4; ++j) {
        float v = acc[fm][fn][j] + bv;
        if (flags & 1) v = fmaxf(v, 0.f);
        if (flags & 2)
          ((float*)C_)[(size_t)e * cB + (size_t)(rowb + j) * N + col] = v;
        else
          ((__hip_bfloat16*)C_)[(size_t)e * cB + (size_t)(rowb + j) * N + col] = __float2bfloat16(v);
      }
    }
  }
}

// ---------------- RoPE on q (interleaved pairs), query only ----------------
__global__ __launch_bounds__(256) void rope_k(float* __restrict__ q) {
  int gid = blockIdx.x * 256 + threadIdx.x;  // T*H*16 = 98304
  int d = gid & 15;
  int h = (gid >> 4) % H;
  int t = gid / (16 * H);
  int s = t & (S - 1);
  float invf = exp2f(-(float)d * (1.0f / 16.0f) * log2f(10000.0f));
  float ang = (float)s * invf;
  float sn, cs;
  sincosf(ang, &sn, &cs);
  float2* p = (float2*)&q[(size_t)t * E + h * HD + 2 * d];
  float2 v = *p;
  *p = make_float2(v.x * cs - v.y * sn, v.x * sn + v.y * cs);
}

// ---------------- attention: one block per (b,h), thread = query row ----------------
__global__ __launch_bounds__(128) void attn_k(const float* __restrict__ q,
                                              const float* __restrict__ kk,
                                              const float* __restrict__ vv,
                                              float* __restrict__ ao) {
  int b = blockIdx.x / H, h = blockIdx.x % H;
  __shared__ float ks[64][32], vs[64][32];
  int tid = threadIdx.x;
  {
    int l = tid >> 1, hf = (tid & 1) * 16;
    const float4* ksrc = (const float4*)&kk[(size_t)(b * L + l) * E + h * HD + hf];
    const float4* vsrc = (const float4*)&vv[(size_t)(b * L + l) * E + h * HD + hf];
    float4* kdst = (float4*)&ks[l][hf];
    float4* vdst = (float4*)&vs[l][hf];
#pragma unroll
    for (int u = 0; u < 4; ++u) { kdst[u] = ksrc[u]; vdst[u] = vsrc[u]; }
  }
  __syncthreads();
  int s = tid;
  const float* qp = &q[(size_t)(b * S + s) * E + h * HD];
  float qv[32];
#pragma unroll
  for (int d = 0; d < 32; ++d) qv[d] = qp[d];
  const float scale = 0.17677669529663687f;  // 1/sqrt(32)
  float mx = -1e30f;
  for (int l = 0; l < 64; ++l) {
    float dot = 0.f;
#pragma unroll
    for (int d = 0; d < 32; ++d) dot += qv[d] * ks[l][d];
    mx = fmaxf(mx, dot * scale);
  }
  float o[32];
#pragma unroll
  for (int d = 0; d < 32; ++d) o[d] = 0.f;
  float sum = 0.f;
  for (int l = 0; l < 64; ++l) {
    float dot = 0.f;
#pragma unroll
    for (int d = 0; d < 32; ++d) dot += qv[d] * ks[l][d];
    float wgt = __expf(dot * scale - mx);
    sum += wgt;
#pragma unroll
    for (int d = 0; d < 32; ++d) o[d] += wgt * vs[l][d];
  }
  float inv = 1.0f / sum;
  float* op = &ao[(size_t)(b * S + s) * E + h * HD];
#pragma unroll
  for (int d = 0; d < 32; ++d) op[d] = o[d] * inv;
}

// ---------------- router ----------------
__global__ __launch_bounds__(64) void router_k(const float* __restrict__ hbuf,
                                               const float* __restrict__ rW,
                                               const float* __restrict__ rb,
                                               float* __restrict__ pk,
                                               int* __restrict__ idx) {
  int t = blockIdx.x * 64 + threadIdx.x;
  float lg[8];
#pragma unroll
  for (int n = 0; n < 8; ++n) lg[n] = rb[n];
  const float* hp = &hbuf[(size_t)t * E];
  for (int e2 = 0; e2 < E; ++e2) {
    float hv = hp[e2];
    const float* wr = &rW[e2 * 8];
#pragma unroll
    for (int n = 0; n < 8; ++n) lg[n] += hv * wr[n];
  }
  float mx = lg[0];
#pragma unroll
  for (int n = 1; n < 8; ++n) mx = fmaxf(mx, lg[n]);
  float p[8], sum = 0.f;
#pragma unroll
  for (int n = 0; n < 8; ++n) { p[n] = __expf(lg[n] - mx); sum += p[n]; }
  float inv = 1.f / sum;
#pragma unroll
  for (int n = 0; n < 8; ++n) p[n] *= inv;
  int i0 = 0;
#pragma unroll
  for (int n = 1; n < 8; ++n) if (p[n] > p[i0]) i0 = n;
  int i1 = (i0 == 0) ? 1 : 0;
#pragma unroll
  for (int n = 0; n < 8; ++n) if (n != i0 && p[n] > p[i1]) i1 = n;
  pk[t * 2] = p[i0];
  pk[t * 2 + 1] = p[i1];
  idx[t * 2] = i0;
  idx[t * 2 + 1] = i1;
}

// ---------------- combine ----------------
__global__ __launch_bounds__(256) void combine_k(const float* __restrict__ x1,
                                                 const float* __restrict__ eo,
                                                 const float* __restrict__ pk,
                                                 const int* __restrict__ idx,
                                                 float* __restrict__ out) {
  int g = blockIdx.x * 256 + threadIdx.x;  // T*E = 196608
  int t = g / E;
  int e = g - t * E;
  int i0 = idx[t * 2], i1 = idx[t * 2 + 1];
  out[g] = x1[g] + pk[t * 2] * eo[((size_t)i0 * T + t) * E + e]
                 + pk[t * 2 + 1] * eo[((size_t)i1 * T + t) * E + e];
}

extern "C" void kernel_launch(void* const* d_in, const int* in_sizes, int n_in,
                              void* d_out, int out_size, void* d_ws, size_t ws_size,
                              hipStream_t stream) {
  const float* x    = (const float*)d_in[0];
  const float* r1w  = (const float*)d_in[1];
  const float* r2w  = (const float*)d_in[2];
  const float* latW = (const float*)d_in[3];
  const float* latb = (const float*)d_in[4];
  const float* qW   = (const float*)d_in[5];
  const float* qb   = (const float*)d_in[6];
  const float* kW   = (const float*)d_in[7];
  const float* kb   = (const float*)d_in[8];
  const float* vW   = (const float*)d_in[9];
  const float* vb   = (const float*)d_in[10];
  const float* oW   = (const float*)d_in[11];
  const float* ob   = (const float*)d_in[12];
  const float* rW   = (const float*)d_in[13];
  const float* rb   = (const float*)d_in[14];
  const float* e1W  = (const float*)d_in[15];
  const float* e1b  = (const float*)d_in[16];
  const float* swW  = (const float*)d_in[17];
  const float* swb  = (const float*)d_in[18];
  const float* e2W  = (const float*)d_in[19];
  const float* e2b  = (const float*)d_in[20];
  float* out = (float*)d_out;

  float* ws = (float*)d_ws;
  float* xn1  = ws;                     // 196608 f32
  float* lat  = ws + 196608;            // 98304
  float* qbuf = ws + 294912;            // 196608
  float* kbuf = ws + 491520;            // 98304
  float* vbuf = ws + 589824;            // 98304
  float* ao   = ws + 688128;            // 196608
  float* x1   = ws + 884736;            // 196608
  float* hbuf = ws + 1081344;           // 196608
  float* pk   = ws + 1277952;           // 2048
  int*   idx  = (int*)(ws + 1280000);   // 2048 ints
  __hip_bfloat16* hb    = (__hip_bfloat16*)(ws + 1282048);  // 196608 bf16
  __hip_bfloat16* e1Wt  = (__hip_bfloat16*)(ws + 1380352);  // 8*768*192 bf16
  __hip_bfloat16* swWt  = (__hip_bfloat16*)(ws + 1970176);  // 8*768*768 bf16
  __hip_bfloat16* e2Wt  = (__hip_bfloat16*)(ws + 4329472);  // 8*192*768 bf16
  __hip_bfloat16* t1    = (__hip_bfloat16*)(ws + 4919296);  // 8*1024*768 bf16
  __hip_bfloat16* t2    = (__hip_bfloat16*)(ws + 8065024);  // 8*1024*768 bf16
  float* eo   = ws + 11210752;          // 8*1024*192 f32
  float* part = ws + 12783616;          // 96*98304 f32

  // 0) expert weight transpose + bf16 convert (independent of everything else)
  tconv_k<<<dim3(E / 32, ED / 32, NEXP), 256, 0, stream>>>(e1W, e1Wt, E, ED);
  tconv_k<<<dim3(ED / 32, ED / 32, NEXP), 256, 0, stream>>>(swW, swWt, ED, ED);
  tconv_k<<<dim3(ED / 32, E / 32, NEXP), 256, 0, stream>>>(e2W, e2Wt, ED, E);

  // 1) rmsnorm1
  rmsnorm_k<<<T, 64, 0, stream>>>(x, r1w, xn1);
  // 2) latent = xn1 @ latW + latb
  lat_partial_k<<<dim3(12, SPLITS), 256, 0, stream>>>(xn1, latW, part);
  lat_reduce_k<<<(8 * LE) / 256, 256, 0, stream>>>(part, latb, lat);
  // 3) q,k,v projections (fp32)
  gemm_k<<<dim3(3, 16, 1), 256, 0, stream>>>(xn1, qW, qb, nullptr, qbuf, T, E, E, 0, 0, 0, 0, 0);
  gemm_k<<<dim3(3, 8, 1), 256, 0, stream>>>(lat, kW, kb, nullptr, kbuf, B * L, E, E, 0, 0, 0, 0, 0);
  gemm_k<<<dim3(3, 8, 1), 256, 0, stream>>>(lat, vW, vb, nullptr, vbuf, B * L, E, E, 0, 0, 0, 0, 0);
  // 4) rope on q
  rope_k<<<(T * H * 16) / 256, 256, 0, stream>>>(qbuf);
  // 5) attention
  attn_k<<<B * H, 128, 0, stream>>>(qbuf, kbuf, vbuf, ao);
  // 6) o-proj + residual
  gemm_k<<<dim3(3, 16, 1), 256, 0, stream>>>(ao, oW, ob, x, x1, T, E, E, 0, 0, 0, 0, 2);
  // 7) rmsnorm2 -> fp32 (router) + bf16 (experts)
  rmsnorm_bf_k<<<T, 64, 0, stream>>>(x1, r2w, hbuf, hb);
  // 8) router (fp32)
  router_k<<<T / 64, 64, 0, stream>>>(hbuf, rW, rb, pk, idx);
  // 9) MoE dense stages, bf16 MFMA
  moe_gemm_k<<<dim3(ED / 64, T / 128, NEXP), 256, 0, stream>>>(
      hb, e1Wt, e1b, t1, T, ED, E, 0, (long)ED * E, ED, (long)T * ED, 0);
  moe_gemm_k<<<dim3(ED / 64, T / 128, NEXP), 256, 0, stream>>>(
      t1, swWt, swb, t2, T, ED, ED, (long)T * ED, (long)ED * ED, ED, (long)T * ED, 1);
  moe_gemm_k<<<dim3(E / 64, T / 128, NEXP), 256, 0, stream>>>(
      t2, e2Wt, e2b, eo, T, E, ED, (long)T * ED, (long)E * ED, E, (long)T * E, 2);
  // 10) combine
  combine_k<<<(T * E) / 256, 256, 0, stream>>>(x1, eo, pk, idx, out);
}

// Round 6
// 348.610 us; speedup vs baseline: 1.7463x; 1.2660x over previous
//
#include <hip/hip_runtime.h>
#include <hip/hip_bf16.h>
#include <math.h>

#define B 8
#define S 128
#define E 192
#define H 6
#define HD 32
#define L 64
#define NEXP 8
#define ED 768
#define T (B*S)     // 1024
#define SE (S*E)    // 24576
#define LE (L*E)    // 12288

#define SPLITS 64
#define ISPAN 384   // 24576/64
#define CHUNK 128

using s8 = __attribute__((ext_vector_type(8))) short;   // 8 bf16 (4 VGPRs)
using f4 = __attribute__((ext_vector_type(4))) float;   // 4 fp32

// ---------------- RMSNorm (one wave per row of 192) ----------------
__global__ __launch_bounds__(64) void rmsnorm_k(const float* __restrict__ x,
                                                const float* __restrict__ w,
                                                float* __restrict__ y) {
  int row = blockIdx.x;
  int lane = threadIdx.x;
  const float* xr = x + (size_t)row * E;
  float v0 = xr[lane], v1 = xr[lane + 64], v2 = xr[lane + 128];
  float s = v0 * v0 + v1 * v1 + v2 * v2;
#pragma unroll
  for (int off = 32; off > 0; off >>= 1) s += __shfl_xor(s, off);
  float inv = rsqrtf(s * (1.0f / E) + 1e-5f);
  float* yr = y + (size_t)row * E;
  yr[lane]       = v0 * inv * w[lane];
  yr[lane + 64]  = v1 * inv * w[lane + 64];
  yr[lane + 128] = v2 * inv * w[lane + 128];
}

// RMSNorm writing fp32 AND bf16 outputs
__global__ __launch_bounds__(64) void rmsnorm_bf_k(const float* __restrict__ x,
                                                   const float* __restrict__ w,
                                                   float* __restrict__ y,
                                                   __hip_bfloat16* __restrict__ yb) {
  int row = blockIdx.x;
  int lane = threadIdx.x;
  const float* xr = x + (size_t)row * E;
  float v0 = xr[lane], v1 = xr[lane + 64], v2 = xr[lane + 128];
  float s = v0 * v0 + v1 * v1 + v2 * v2;
#pragma unroll
  for (int off = 32; off > 0; off >>= 1) s += __shfl_xor(s, off);
  float inv = rsqrtf(s * (1.0f / E) + 1e-5f);
  float r0 = v0 * inv * w[lane];
  float r1 = v1 * inv * w[lane + 64];
  float r2 = v2 * inv * w[lane + 128];
  float* yr = y + (size_t)row * E;
  __hip_bfloat16* yrb = yb + (size_t)row * E;
  yr[lane] = r0; yr[lane + 64] = r1; yr[lane + 128] = r2;
  yrb[lane] = __float2bfloat16(r0);
  yrb[lane + 64] = __float2bfloat16(r1);
  yrb[lane + 128] = __float2bfloat16(r2);
}

// ---------------- latent GEMM: partials over i-splits ----------------
// latent[b][j] = sum_i xn[b][i] * latW[i][j]; grid (12, 64) = 768 blocks = 3/CU.
__global__ __launch_bounds__(256) void lat_partial_k(const float* __restrict__ xn,
                                                     const float* __restrict__ latW,
                                                     float* __restrict__ part) {
  const int tid = threadIdx.x;
  const int j = blockIdx.x * 1024 + tid * 4;
  const int i0 = blockIdx.y * ISPAN;
  __shared__ float xs[CHUNK][8];
  f4 acc[8];
#pragma unroll
  for (int b = 0; b < 8; ++b) acc[b] = (f4){0.f, 0.f, 0.f, 0.f};
  for (int c = 0; c < ISPAN; c += CHUNK) {
    float* xsf = (float*)xs;
    __syncthreads();
    for (int l = tid; l < CHUNK * 8; l += 256) {
      int ii = l >> 3, b = l & 7;
      xsf[l] = xn[(size_t)b * SE + i0 + c + ii];
    }
    __syncthreads();
#pragma unroll 8
    for (int ii = 0; ii < CHUNK; ++ii) {
      const f4 w = __builtin_nontemporal_load(
          (const f4*)&latW[(size_t)(i0 + c + ii) * LE + j]);
#pragma unroll
      for (int b = 0; b < 8; ++b) {
        float xv = xs[ii][b];
        acc[b][0] += xv * w[0];
        acc[b][1] += xv * w[1];
        acc[b][2] += xv * w[2];
        acc[b][3] += xv * w[3];
      }
    }
  }
#pragma unroll
  for (int b = 0; b < 8; ++b)
    *(f4*)&part[((size_t)blockIdx.y * 8 + b) * LE + j] = acc[b];
}

__global__ __launch_bounds__(256) void lat_reduce_k(const float* __restrict__ part,
                                                    const float* __restrict__ latb,
                                                    float* __restrict__ lat) {
  int g = blockIdx.x * 256 + threadIdx.x;  // < 8*LE
  int b = g / LE, j = g - b * LE;
  float s = latb[j];
  for (int sp = 0; sp < SPLITS; ++sp) s += part[((size_t)sp * 8 + b) * LE + j];
  lat[g] = s;
}

// ---------------- fused q/k/v projections: one dispatch, z selects op ----------------
// 64x64 tile, BK=16, N=K=E. z=0: q=xn1@qW (M=T); z=1: k=lat@kW; z=2: v=lat@vW (M=B*L).
__global__ __launch_bounds__(256) void qkv_k(const float* __restrict__ xn,
                                             const float* __restrict__ lat,
                                             const float* __restrict__ qW, const float* __restrict__ qb,
                                             const float* __restrict__ kW, const float* __restrict__ kb,
                                             const float* __restrict__ vW, const float* __restrict__ vb,
                                             float* __restrict__ qo,
                                             float* __restrict__ ko,
                                             float* __restrict__ vo) {
  const int z = blockIdx.z;
  const float* A = (z == 0) ? xn : lat;
  const float* W = (z == 0) ? qW : (z == 1) ? kW : vW;
  const float* bp = (z == 0) ? qb : (z == 1) ? kb : vb;
  float* C = (z == 0) ? qo : (z == 1) ? ko : vo;
  const int M = (z == 0) ? T : (B * L);
  const int m0 = blockIdx.y * 64;
  if (m0 >= M) return;
  const int n0 = blockIdx.x * 64;
  __shared__ float As[16][64];
  __shared__ float Ws[16][64];
  const int tid = threadIdx.x;
  const int tx = tid & 15, ty = tid >> 4;
  const int arow = tid >> 2, acol = (tid & 3) << 2;
  const int wrow = tid >> 4, wcol = (tid & 15) << 2;
  float acc[4][4] = {{0.f}};
  for (int kb2 = 0; kb2 < E; kb2 += 16) {
    float4 a = *(const float4*)&A[(size_t)(m0 + arow) * E + kb2 + acol];
    As[acol][arow] = a.x;
    As[acol + 1][arow] = a.y;
    As[acol + 2][arow] = a.z;
    As[acol + 3][arow] = a.w;
    *(float4*)&Ws[wrow][wcol] = *(const float4*)&W[(size_t)(kb2 + wrow) * E + n0 + wcol];
    __syncthreads();
#pragma unroll
    for (int k = 0; k < 16; ++k) {
      float4 a4 = *(const float4*)&As[k][ty << 2];
      float4 w4 = *(const float4*)&Ws[k][tx << 2];
      acc[0][0] += a4.x * w4.x; acc[0][1] += a4.x * w4.y; acc[0][2] += a4.x * w4.z; acc[0][3] += a4.x * w4.w;
      acc[1][0] += a4.y * w4.x; acc[1][1] += a4.y * w4.y; acc[1][2] += a4.y * w4.z; acc[1][3] += a4.y * w4.w;
      acc[2][0] += a4.z * w4.x; acc[2][1] += a4.z * w4.y; acc[2][2] += a4.z * w4.z; acc[2][3] += a4.z * w4.w;
      acc[3][0] += a4.w * w4.x; acc[3][1] += a4.w * w4.y; acc[3][2] += a4.w * w4.z; acc[3][3] += a4.w * w4.w;
    }
    __syncthreads();
  }
#pragma unroll
  for (int i = 0; i < 4; ++i) {
    int m = m0 + (ty << 2) + i;
#pragma unroll
    for (int jj = 0; jj < 4; ++jj) {
      int n = n0 + (tx << 2) + jj;
      C[(size_t)m * E + n] = acc[i][jj] + bp[n];
    }
  }
}

// ---------------- generic fp32 GEMM (o-proj) ----------------
__global__ __launch_bounds__(256) void gemm_k(const float* __restrict__ A,
                                              const float* __restrict__ W,
                                              const float* __restrict__ bias,
                                              const float* __restrict__ resid,
                                              float* __restrict__ C,
                                              int M, int N, int K,
                                              int flags) {
  const int n0 = blockIdx.x * 64;
  const int m0 = blockIdx.y * 64;
  __shared__ float As[16][64];
  __shared__ float Ws[16][64];
  const int tid = threadIdx.x;
  const int tx = tid & 15, ty = tid >> 4;
  const int arow = tid >> 2, acol = (tid & 3) << 2;
  const int wrow = tid >> 4, wcol = (tid & 15) << 2;
  float acc[4][4] = {{0.f}};
  for (int kb = 0; kb < K; kb += 16) {
    float4 a = *(const float4*)&A[(size_t)(m0 + arow) * K + kb + acol];
    As[acol][arow] = a.x;
    As[acol + 1][arow] = a.y;
    As[acol + 2][arow] = a.z;
    As[acol + 3][arow] = a.w;
    *(float4*)&Ws[wrow][wcol] = *(const float4*)&W[(size_t)(kb + wrow) * N + n0 + wcol];
    __syncthreads();
#pragma unroll
    for (int k = 0; k < 16; ++k) {
      float4 a4 = *(const float4*)&As[k][ty << 2];
      float4 w4 = *(const float4*)&Ws[k][tx << 2];
      acc[0][0] += a4.x * w4.x; acc[0][1] += a4.x * w4.y; acc[0][2] += a4.x * w4.z; acc[0][3] += a4.x * w4.w;
      acc[1][0] += a4.y * w4.x; acc[1][1] += a4.y * w4.y; acc[1][2] += a4.y * w4.z; acc[1][3] += a4.y * w4.w;
      acc[2][0] += a4.z * w4.x; acc[2][1] += a4.z * w4.y; acc[2][2] += a4.z * w4.z; acc[2][3] += a4.z * w4.w;
      acc[3][0] += a4.w * w4.x; acc[3][1] += a4.w * w4.y; acc[3][2] += a4.w * w4.z; acc[3][3] += a4.w * w4.w;
    }
    __syncthreads();
  }
#pragma unroll
  for (int i = 0; i < 4; ++i) {
    int m = m0 + (ty << 2) + i;
#pragma unroll
    for (int j = 0; j < 4; ++j) {
      int n = n0 + (tx << 2) + j;
      float v = acc[i][j];
      if (bias) v += bias[n];
      if (flags & 1) v = fmaxf(v, 0.f);
      if (flags & 2) v += resid[(size_t)m * N + n];
      C[(size_t)m * N + n] = v;
    }
  }
}

// ---------------- weight transpose + fp32->bf16: out[n][k] = in[k][n] ----------------
__global__ __launch_bounds__(256) void tconv_k(const float* __restrict__ in,
                                               __hip_bfloat16* __restrict__ out,
                                               int K, int N) {
  const int e = blockIdx.z;
  in += (size_t)e * K * N;
  out += (size_t)e * N * K;
  __shared__ float tile[32][33];
  int tx = threadIdx.x & 31, r8 = threadIdx.x >> 5;
  int k0 = blockIdx.x * 32, n0 = blockIdx.y * 32;
#pragma unroll
  for (int i = 0; i < 4; ++i)
    tile[r8 + 8 * i][tx] = in[(size_t)(k0 + r8 + 8 * i) * N + n0 + tx];
  __syncthreads();
#pragma unroll
  for (int i = 0; i < 4; ++i) {
    int nr = r8 + 8 * i;
    out[(size_t)(n0 + nr) * K + k0 + tx] = __float2bfloat16(tile[tx][nr]);
  }
}

// ---------------- bf16 MFMA GEMM: C = act(A @ Wt^T + bias) ----------------
__global__ __launch_bounds__(256) void moe_gemm_k(const __hip_bfloat16* __restrict__ A_,
                                                  const __hip_bfloat16* __restrict__ Wt_,
                                                  const float* __restrict__ bias_,
                                                  void* __restrict__ C_,
                                                  int M, int N, int K,
                                                  long aB, long wB, long bB, long cB,
                                                  int flags) {
  const int e = blockIdx.z;
  const short* A = (const short*)A_ + (size_t)e * aB;
  const short* Wt = (const short*)Wt_ + (size_t)e * wB;
  const float* bias = bias_ + (size_t)e * bB;
  const int n0 = blockIdx.x * 64;
  const int m0 = blockIdx.y * 128;
  __shared__ short As[128 * 64];  // 16 KB, XOR-swizzled 16B slots
  __shared__ short Bs[64 * 64];   // 8 KB
  const int tid = threadIdx.x;
  const int lane = tid & 63, wid = tid >> 6;
  const int wr = wid >> 1, wc = wid & 1;
  const int lr = lane & 15, lg = lane >> 4;
  f4 acc[4][2];
#pragma unroll
  for (int fm = 0; fm < 4; ++fm)
#pragma unroll
    for (int fn = 0; fn < 2; ++fn) acc[fm][fn] = (f4){0.f, 0.f, 0.f, 0.f};

  for (int kb = 0; kb < K; kb += 64) {
    __syncthreads();
#pragma unroll
    for (int p = 0; p < 4; ++p) {   // stage A: 128 rows x 64 bf16
      int eidx = p * 256 + tid;
      int row = eidx >> 3, slot = eidx & 7;
      s8 v = *(const s8*)(A + (size_t)(m0 + row) * K + kb + slot * 8);
      *(s8*)&As[row * 64 + ((slot ^ (row & 7)) << 3)] = v;
    }
#pragma unroll
    for (int p = 0; p < 2; ++p) {   // stage B: 64 rows x 64 bf16
      int eidx = p * 256 + tid;
      int row = eidx >> 3, slot = eidx & 7;
      s8 v = *(const s8*)(Wt + (size_t)(n0 + row) * K + kb + slot * 8);
      *(s8*)&Bs[row * 64 + ((slot ^ (row & 7)) << 3)] = v;
    }
    __syncthreads();
#pragma unroll
    for (int kk = 0; kk < 64; kk += 32) {
      const int sb = (kk >> 3) + lg;
      s8 af[4], bf[2];
#pragma unroll
      for (int fm = 0; fm < 4; ++fm) {
        int row = wr * 64 + fm * 16 + lr;
        af[fm] = *(const s8*)&As[row * 64 + ((sb ^ (row & 7)) << 3)];
      }
#pragma unroll
      for (int fn = 0; fn < 2; ++fn) {
        int row = wc * 32 + fn * 16 + lr;
        bf[fn] = *(const s8*)&Bs[row * 64 + ((sb ^ (row & 7)) << 3)];
      }
#pragma unroll
      for (int fm = 0; fm < 4; ++fm)
#pragma unroll
        for (int fn = 0; fn < 2; ++fn)
          acc[fm][fn] = __builtin_amdgcn_mfma_f32_16x16x32_bf16(af[fm], bf[fn], acc[fm][fn], 0, 0, 0);
    }
  }
#pragma unroll
  for (int fm = 0; fm < 4; ++fm) {
#pragma unroll
    for (int fn = 0; fn < 2; ++fn) {
      int col = n0 + wc * 32 + fn * 16 + lr;
      int rowb = m0 + wr * 64 + fm * 16 + lg * 4;
      float bv = bias[col];
#pragma unroll
      for (int j = 0; j < 4; ++j) {
        float v = acc[fm][fn][j] + bv;
        if (flags & 1) v = fmaxf(v, 0.f);
        if (flags & 2)
          ((float*)C_)[(size_t)e * cB + (size_t)(rowb + j) * N + col] = v;
        else
          ((__hip_bfloat16*)C_)[(size_t)e * cB + (size_t)(rowb + j) * N + col] = __float2bfloat16(v);
      }
    }
  }
}

// ---------------- attention (RoPE on q fused): one block per (b,h) ----------------
__global__ __launch_bounds__(128) void attn_k(const float* __restrict__ q,
                                              const float* __restrict__ kk,
                                              const float* __restrict__ vv,
                                              float* __restrict__ ao) {
  int b = blockIdx.x / H, h = blockIdx.x % H;
  __shared__ float ks[64][32], vs[64][32];
  int tid = threadIdx.x;
  {
    int l = tid >> 1, hf = (tid & 1) * 16;
    const float4* ksrc = (const float4*)&kk[(size_t)(b * L + l) * E + h * HD + hf];
    const float4* vsrc = (const float4*)&vv[(size_t)(b * L + l) * E + h * HD + hf];
    float4* kdst = (float4*)&ks[l][hf];
    float4* vdst = (float4*)&vs[l][hf];
#pragma unroll
    for (int u = 0; u < 4; ++u) { kdst[u] = ksrc[u]; vdst[u] = vsrc[u]; }
  }
  __syncthreads();
  int s = tid;
  const float* qp = &q[(size_t)(b * S + s) * E + h * HD];
  float qv[32];
#pragma unroll
  for (int d = 0; d < 32; ++d) qv[d] = qp[d];
  // RoPE (interleaved pairs): inv_freq = 10000^(-d/16), angle = s * inv_freq
#pragma unroll
  for (int d = 0; d < 16; ++d) {
    float invf = exp2f(-(float)d * (13.287712379549449f / 16.0f));
    float ang = (float)s * invf;
    float sn, cs;
    __sincosf(ang, &sn, &cs);
    float x1 = qv[2 * d], x2 = qv[2 * d + 1];
    qv[2 * d] = x1 * cs - x2 * sn;
    qv[2 * d + 1] = x1 * sn + x2 * cs;
  }
  const float scale = 0.17677669529663687f;  // 1/sqrt(32)
  float mx = -1e30f;
  for (int l = 0; l < 64; ++l) {
    float dot = 0.f;
#pragma unroll
    for (int d = 0; d < 32; ++d) dot += qv[d] * ks[l][d];
    mx = fmaxf(mx, dot * scale);
  }
  float o[32];
#pragma unroll
  for (int d = 0; d < 32; ++d) o[d] = 0.f;
  float sum = 0.f;
  for (int l = 0; l < 64; ++l) {
    float dot = 0.f;
#pragma unroll
    for (int d = 0; d < 32; ++d) dot += qv[d] * ks[l][d];
    float wgt = __expf(dot * scale - mx);
    sum += wgt;
#pragma unroll
    for (int d = 0; d < 32; ++d) o[d] += wgt * vs[l][d];
  }
  float inv = 1.0f / sum;
  float* op = &ao[(size_t)(b * S + s) * E + h * HD];
#pragma unroll
  for (int d = 0; d < 32; ++d) op[d] = o[d] * inv;
}

// ---------------- router ----------------
__global__ __launch_bounds__(64) void router_k(const float* __restrict__ hbuf,
                                               const float* __restrict__ rW,
                                               const float* __restrict__ rb,
                                               float* __restrict__ pk,
                                               int* __restrict__ idx) {
  int t = blockIdx.x * 64 + threadIdx.x;
  float lg[8];
#pragma unroll
  for (int n = 0; n < 8; ++n) lg[n] = rb[n];
  const float* hp = &hbuf[(size_t)t * E];
  for (int e2 = 0; e2 < E; ++e2) {
    float hv = hp[e2];
    const float* wr = &rW[e2 * 8];
#pragma unroll
    for (int n = 0; n < 8; ++n) lg[n] += hv * wr[n];
  }
  float mx = lg[0];
#pragma unroll
  for (int n = 1; n < 8; ++n) mx = fmaxf(mx, lg[n]);
  float p[8], sum = 0.f;
#pragma unroll
  for (int n = 0; n < 8; ++n) { p[n] = __expf(lg[n] - mx); sum += p[n]; }
  float inv = 1.f / sum;
#pragma unroll
  for (int n = 0; n < 8; ++n) p[n] *= inv;
  int i0 = 0;
#pragma unroll
  for (int n = 1; n < 8; ++n) if (p[n] > p[i0]) i0 = n;
  int i1 = (i0 == 0) ? 1 : 0;
#pragma unroll
  for (int n = 0; n < 8; ++n) if (n != i0 && p[n] > p[i1]) i1 = n;
  pk[t * 2] = p[i0];
  pk[t * 2 + 1] = p[i1];
  idx[t * 2] = i0;
  idx[t * 2 + 1] = i1;
}

// ---------------- combine ----------------
__global__ __launch_bounds__(256) void combine_k(const float* __restrict__ x1,
                                                 const float* __restrict__ eo,
                                                 const float* __restrict__ pk,
                                                 const int* __restrict__ idx,
                                                 float* __restrict__ out) {
  int g = blockIdx.x * 256 + threadIdx.x;  // T*E = 196608
  int t = g / E;
  int e = g - t * E;
  int i0 = idx[t * 2], i1 = idx[t * 2 + 1];
  out[g] = x1[g] + pk[t * 2] * eo[((size_t)i0 * T + t) * E + e]
                 + pk[t * 2 + 1] * eo[((size_t)i1 * T + t) * E + e];
}

extern "C" void kernel_launch(void* const* d_in, const int* in_sizes, int n_in,
                              void* d_out, int out_size, void* d_ws, size_t ws_size,
                              hipStream_t stream) {
  const float* x    = (const float*)d_in[0];
  const float* r1w  = (const float*)d_in[1];
  const float* r2w  = (const float*)d_in[2];
  const float* latW = (const float*)d_in[3];
  const float* latb = (const float*)d_in[4];
  const float* qW   = (const float*)d_in[5];
  const float* qb   = (const float*)d_in[6];
  const float* kW   = (const float*)d_in[7];
  const float* kb   = (const float*)d_in[8];
  const float* vW   = (const float*)d_in[9];
  const float* vb   = (const float*)d_in[10];
  const float* oW   = (const float*)d_in[11];
  const float* ob   = (const float*)d_in[12];
  const float* rW   = (const float*)d_in[13];
  const float* rb   = (const float*)d_in[14];
  const float* e1W  = (const float*)d_in[15];
  const float* e1b  = (const float*)d_in[16];
  const float* swW  = (const float*)d_in[17];
  const float* swb  = (const float*)d_in[18];
  const float* e2W  = (const float*)d_in[19];
  const float* e2b  = (const float*)d_in[20];
  float* out = (float*)d_out;

  float* ws = (float*)d_ws;
  float* xn1  = ws;                     // 196608 f32
  float* lat  = ws + 196608;            // 98304
  float* qbuf = ws + 294912;            // 196608
  float* kbuf = ws + 491520;            // 98304
  float* vbuf = ws + 589824;            // 98304
  float* ao   = ws + 688128;            // 196608
  float* x1   = ws + 884736;            // 196608
  float* hbuf = ws + 1081344;           // 196608
  float* pk   = ws + 1277952;           // 2048
  int*   idx  = (int*)(ws + 1280000);   // 2048 ints
  __hip_bfloat16* hb    = (__hip_bfloat16*)(ws + 1282048);  // 196608 bf16
  __hip_bfloat16* e1Wt  = (__hip_bfloat16*)(ws + 1380352);  // 8*768*192 bf16
  __hip_bfloat16* swWt  = (__hip_bfloat16*)(ws + 1970176);  // 8*768*768 bf16
  __hip_bfloat16* e2Wt  = (__hip_bfloat16*)(ws + 4329472);  // 8*192*768 bf16
  __hip_bfloat16* t1    = (__hip_bfloat16*)(ws + 4919296);  // 8*1024*768 bf16
  __hip_bfloat16* t2    = (__hip_bfloat16*)(ws + 8065024);  // 8*1024*768 bf16
  float* eo   = ws + 11210752;          // 8*1024*192 f32
  float* part = ws + 12783616;          // 64*98304 f32

  // 0) expert weight transpose + bf16 convert
  tconv_k<<<dim3(E / 32, ED / 32, NEXP), 256, 0, stream>>>(e1W, e1Wt, E, ED);
  tconv_k<<<dim3(ED / 32, ED / 32, NEXP), 256, 0, stream>>>(swW, swWt, ED, ED);
  tconv_k<<<dim3(ED / 32, E / 32, NEXP), 256, 0, stream>>>(e2W, e2Wt, ED, E);

  // 1) rmsnorm1
  rmsnorm_k<<<T, 64, 0, stream>>>(x, r1w, xn1);
  // 2) latent = xn1 @ latW + latb
  lat_partial_k<<<dim3(12, SPLITS), 256, 0, stream>>>(xn1, latW, part);
  lat_reduce_k<<<(8 * LE) / 256, 256, 0, stream>>>(part, latb, lat);
  // 3) q,k,v projections fused (z: 0=q, 1=k, 2=v; y-guard for M)
  qkv_k<<<dim3(3, 16, 3), 256, 0, stream>>>(xn1, lat, qW, qb, kW, kb, vW, vb,
                                            qbuf, kbuf, vbuf);
  // 4) attention (rope fused on q)
  attn_k<<<B * H, 128, 0, stream>>>(qbuf, kbuf, vbuf, ao);
  // 5) o-proj + residual
  gemm_k<<<dim3(3, 16), 256, 0, stream>>>(ao, oW, ob, x, x1, T, E, E, 2);
  // 6) rmsnorm2 -> fp32 (router) + bf16 (experts)
  rmsnorm_bf_k<<<T, 64, 0, stream>>>(x1, r2w, hbuf, hb);
  // 7) router (fp32)
  router_k<<<T / 64, 64, 0, stream>>>(hbuf, rW, rb, pk, idx);
  // 8) MoE dense stages, bf16 MFMA
  moe_gemm_k<<<dim3(ED / 64, T / 128, NEXP), 256, 0, stream>>>(
      hb, e1Wt, e1b, t1, T, ED, E, 0, (long)ED * E, ED, (long)T * ED, 0);
  moe_gemm_k<<<dim3(ED / 64, T / 128, NEXP), 256, 0, stream>>>(
      t1, swWt, swb, t2, T, ED, ED, (long)T * ED, (long)ED * ED, ED, (long)T * ED, 1);
  moe_gemm_k<<<dim3(E / 64, T / 128, NEXP), 256, 0, stream>>>(
      t2, e2Wt, e2b, eo, T, E, ED, (long)T * ED, (long)E * ED, E, (long)T * E, 2);
  // 9) combine
  combine_k<<<(T * E) / 256, 256, 0, stream>>>(x1, eo, pk, idx, out);
}

// Round 7
// 340.354 us; speedup vs baseline: 1.7887x; 1.0243x over previous
//
#include <hip/hip_runtime.h>
#include <hip/hip_bf16.h>
#include <math.h>

#define B 8
#define S 128
#define E 192
#define H 6
#define HD 32
#define L 64
#define NEXP 8
#define ED 768
#define T (B*S)     // 1024
#define SE (S*E)    // 24576
#define LE (L*E)    // 12288

#define SPLITS 64
#define ISPAN 384   // 24576/64
#define CHUNK 128

using s8 = __attribute__((ext_vector_type(8))) short;   // 8 bf16 (4 VGPRs)
using f4 = __attribute__((ext_vector_type(4))) float;   // 4 fp32

// ---------------- RMSNorm (one wave per row of 192) ----------------
__global__ __launch_bounds__(64) void rmsnorm_k(const float* __restrict__ x,
                                                const float* __restrict__ w,
                                                float* __restrict__ y) {
  int row = blockIdx.x;
  int lane = threadIdx.x;
  const float* xr = x + (size_t)row * E;
  float v0 = xr[lane], v1 = xr[lane + 64], v2 = xr[lane + 128];
  float s = v0 * v0 + v1 * v1 + v2 * v2;
#pragma unroll
  for (int off = 32; off > 0; off >>= 1) s += __shfl_xor(s, off);
  float inv = rsqrtf(s * (1.0f / E) + 1e-5f);
  float* yr = y + (size_t)row * E;
  yr[lane]       = v0 * inv * w[lane];
  yr[lane + 64]  = v1 * inv * w[lane + 64];
  yr[lane + 128] = v2 * inv * w[lane + 128];
}

// ---------------- latent GEMM: partials over i-splits ----------------
__global__ __launch_bounds__(256) void lat_partial_k(const float* __restrict__ xn,
                                                     const float* __restrict__ latW,
                                                     float* __restrict__ part) {
  const int tid = threadIdx.x;
  const int j = blockIdx.x * 1024 + tid * 4;
  const int i0 = blockIdx.y * ISPAN;
  __shared__ float xs[CHUNK][8];
  f4 acc[8];
#pragma unroll
  for (int b = 0; b < 8; ++b) acc[b] = (f4){0.f, 0.f, 0.f, 0.f};
  for (int c = 0; c < ISPAN; c += CHUNK) {
    float* xsf = (float*)xs;
    __syncthreads();
    for (int l = tid; l < CHUNK * 8; l += 256) {
      int ii = l >> 3, b = l & 7;
      xsf[l] = xn[(size_t)b * SE + i0 + c + ii];
    }
    __syncthreads();
#pragma unroll 8
    for (int ii = 0; ii < CHUNK; ++ii) {
      const f4 w = __builtin_nontemporal_load(
          (const f4*)&latW[(size_t)(i0 + c + ii) * LE + j]);
#pragma unroll
      for (int b = 0; b < 8; ++b) {
        float xv = xs[ii][b];
        acc[b][0] += xv * w[0];
        acc[b][1] += xv * w[1];
        acc[b][2] += xv * w[2];
        acc[b][3] += xv * w[3];
      }
    }
  }
#pragma unroll
  for (int b = 0; b < 8; ++b)
    *(f4*)&part[((size_t)blockIdx.y * 8 + b) * LE + j] = acc[b];
}

__global__ __launch_bounds__(256) void lat_reduce_k(const float* __restrict__ part,
                                                    const float* __restrict__ latb,
                                                    float* __restrict__ lat) {
  int g = blockIdx.x * 256 + threadIdx.x;  // < 8*LE
  int b = g / LE, j = g - b * LE;
  float s = latb[j];
  for (int sp = 0; sp < SPLITS; ++sp) s += part[((size_t)sp * 8 + b) * LE + j];
  lat[g] = s;
}

// ---------------- fused q/k/v projections ----------------
__global__ __launch_bounds__(256) void qkv_k(const float* __restrict__ xn,
                                             const float* __restrict__ lat,
                                             const float* __restrict__ qW, const float* __restrict__ qb,
                                             const float* __restrict__ kW, const float* __restrict__ kb,
                                             const float* __restrict__ vW, const float* __restrict__ vb,
                                             float* __restrict__ qo,
                                             float* __restrict__ ko,
                                             float* __restrict__ vo) {
  const int z = blockIdx.z;
  const float* A = (z == 0) ? xn : lat;
  const float* W = (z == 0) ? qW : (z == 1) ? kW : vW;
  const float* bp = (z == 0) ? qb : (z == 1) ? kb : vb;
  float* C = (z == 0) ? qo : (z == 1) ? ko : vo;
  const int M = (z == 0) ? T : (B * L);
  const int m0 = blockIdx.y * 64;
  if (m0 >= M) return;
  const int n0 = blockIdx.x * 64;
  __shared__ float As[16][64];
  __shared__ float Ws[16][64];
  const int tid = threadIdx.x;
  const int tx = tid & 15, ty = tid >> 4;
  const int arow = tid >> 2, acol = (tid & 3) << 2;
  const int wrow = tid >> 4, wcol = (tid & 15) << 2;
  float acc[4][4] = {{0.f}};
  for (int kb2 = 0; kb2 < E; kb2 += 16) {
    float4 a = *(const float4*)&A[(size_t)(m0 + arow) * E + kb2 + acol];
    As[acol][arow] = a.x;
    As[acol + 1][arow] = a.y;
    As[acol + 2][arow] = a.z;
    As[acol + 3][arow] = a.w;
    *(float4*)&Ws[wrow][wcol] = *(const float4*)&W[(size_t)(kb2 + wrow) * E + n0 + wcol];
    __syncthreads();
#pragma unroll
    for (int k = 0; k < 16; ++k) {
      float4 a4 = *(const float4*)&As[k][ty << 2];
      float4 w4 = *(const float4*)&Ws[k][tx << 2];
      acc[0][0] += a4.x * w4.x; acc[0][1] += a4.x * w4.y; acc[0][2] += a4.x * w4.z; acc[0][3] += a4.x * w4.w;
      acc[1][0] += a4.y * w4.x; acc[1][1] += a4.y * w4.y; acc[1][2] += a4.y * w4.z; acc[1][3] += a4.y * w4.w;
      acc[2][0] += a4.z * w4.x; acc[2][1] += a4.z * w4.y; acc[2][2] += a4.z * w4.z; acc[2][3] += a4.z * w4.w;
      acc[3][0] += a4.w * w4.x; acc[3][1] += a4.w * w4.y; acc[3][2] += a4.w * w4.z; acc[3][3] += a4.w * w4.w;
    }
    __syncthreads();
  }
#pragma unroll
  for (int i = 0; i < 4; ++i) {
    int m = m0 + (ty << 2) + i;
#pragma unroll
    for (int jj = 0; jj < 4; ++jj) {
      int n = n0 + (tx << 2) + jj;
      C[(size_t)m * E + n] = acc[i][jj] + bp[n];
    }
  }
}

// ---------------- generic fp32 GEMM (o-proj) ----------------
__global__ __launch_bounds__(256) void gemm_k(const float* __restrict__ A,
                                              const float* __restrict__ W,
                                              const float* __restrict__ bias,
                                              const float* __restrict__ resid,
                                              float* __restrict__ C,
                                              int M, int N, int K,
                                              int flags) {
  const int n0 = blockIdx.x * 64;
  const int m0 = blockIdx.y * 64;
  __shared__ float As[16][64];
  __shared__ float Ws[16][64];
  const int tid = threadIdx.x;
  const int tx = tid & 15, ty = tid >> 4;
  const int arow = tid >> 2, acol = (tid & 3) << 2;
  const int wrow = tid >> 4, wcol = (tid & 15) << 2;
  float acc[4][4] = {{0.f}};
  for (int kb = 0; kb < K; kb += 16) {
    float4 a = *(const float4*)&A[(size_t)(m0 + arow) * K + kb + acol];
    As[acol][arow] = a.x;
    As[acol + 1][arow] = a.y;
    As[acol + 2][arow] = a.z;
    As[acol + 3][arow] = a.w;
    *(float4*)&Ws[wrow][wcol] = *(const float4*)&W[(size_t)(kb + wrow) * N + n0 + wcol];
    __syncthreads();
#pragma unroll
    for (int k = 0; k < 16; ++k) {
      float4 a4 = *(const float4*)&As[k][ty << 2];
      float4 w4 = *(const float4*)&Ws[k][tx << 2];
      acc[0][0] += a4.x * w4.x; acc[0][1] += a4.x * w4.y; acc[0][2] += a4.x * w4.z; acc[0][3] += a4.x * w4.w;
      acc[1][0] += a4.y * w4.x; acc[1][1] += a4.y * w4.y; acc[1][2] += a4.y * w4.z; acc[1][3] += a4.y * w4.w;
      acc[2][0] += a4.z * w4.x; acc[2][1] += a4.z * w4.y; acc[2][2] += a4.z * w4.z; acc[2][3] += a4.z * w4.w;
      acc[3][0] += a4.w * w4.x; acc[3][1] += a4.w * w4.y; acc[3][2] += a4.w * w4.z; acc[3][3] += a4.w * w4.w;
    }
    __syncthreads();
  }
#pragma unroll
  for (int i = 0; i < 4; ++i) {
    int m = m0 + (ty << 2) + i;
#pragma unroll
    for (int j = 0; j < 4; ++j) {
      int n = n0 + (tx << 2) + j;
      float v = acc[i][j];
      if (bias) v += bias[n];
      if (flags & 1) v = fmaxf(v, 0.f);
      if (flags & 2) v += resid[(size_t)m * N + n];
      C[(size_t)m * N + n] = v;
    }
  }
}

// ---------------- weight transpose + fp32->bf16 ----------------
__global__ __launch_bounds__(256) void tconv_k(const float* __restrict__ in,
                                               __hip_bfloat16* __restrict__ out,
                                               int K, int N) {
  const int e = blockIdx.z;
  in += (size_t)e * K * N;
  out += (size_t)e * N * K;
  __shared__ float tile[32][33];
  int tx = threadIdx.x & 31, r8 = threadIdx.x >> 5;
  int k0 = blockIdx.x * 32, n0 = blockIdx.y * 32;
#pragma unroll
  for (int i = 0; i < 4; ++i)
    tile[r8 + 8 * i][tx] = in[(size_t)(k0 + r8 + 8 * i) * N + n0 + tx];
  __syncthreads();
#pragma unroll
  for (int i = 0; i < 4; ++i) {
    int nr = r8 + 8 * i;
    out[(size_t)(n0 + nr) * K + k0 + tx] = __float2bfloat16(tile[tx][nr]);
  }
}

// ---------------- fused rmsnorm2 + router: one wave per token ----------------
__global__ __launch_bounds__(64) void router_rms_k(const float* __restrict__ x1,
                                                   const float* __restrict__ w,
                                                   const float* __restrict__ rW,
                                                   const float* __restrict__ rb,
                                                   __hip_bfloat16* __restrict__ hb,
                                                   float* __restrict__ pk,
                                                   int* __restrict__ idx) {
  int t = blockIdx.x;
  int lane = threadIdx.x;
  const float* xr = x1 + (size_t)t * E;
  float v0 = xr[lane], v1 = xr[lane + 64], v2 = xr[lane + 128];
  float s = v0 * v0 + v1 * v1 + v2 * v2;
#pragma unroll
  for (int off = 32; off > 0; off >>= 1) s += __shfl_xor(s, off);
  float inv = rsqrtf(s * (1.0f / E) + 1e-5f);
  float r0 = v0 * inv * w[lane];
  float r1 = v1 * inv * w[lane + 64];
  float r2 = v2 * inv * w[lane + 128];
  __hip_bfloat16* yrb = hb + (size_t)t * E;
  yrb[lane] = __float2bfloat16(r0);
  yrb[lane + 64] = __float2bfloat16(r1);
  yrb[lane + 128] = __float2bfloat16(r2);
  // logits: partial per lane over its 3 elements, then wave-reduce
  float lg[8];
#pragma unroll
  for (int n = 0; n < 8; ++n)
    lg[n] = r0 * rW[lane * 8 + n] + r1 * rW[(lane + 64) * 8 + n] + r2 * rW[(lane + 128) * 8 + n];
#pragma unroll
  for (int n = 0; n < 8; ++n)
#pragma unroll
    for (int off = 32; off > 0; off >>= 1) lg[n] += __shfl_xor(lg[n], off);
  if (lane == 0) {
#pragma unroll
    for (int n = 0; n < 8; ++n) lg[n] += rb[n];
    float mx = lg[0];
#pragma unroll
    for (int n = 1; n < 8; ++n) mx = fmaxf(mx, lg[n]);
    float p[8], sum = 0.f;
#pragma unroll
    for (int n = 0; n < 8; ++n) { p[n] = __expf(lg[n] - mx); sum += p[n]; }
    float isum = 1.f / sum;
#pragma unroll
    for (int n = 0; n < 8; ++n) p[n] *= isum;
    int i0 = 0;
#pragma unroll
    for (int n = 1; n < 8; ++n) if (p[n] > p[i0]) i0 = n;
    int i1 = (i0 == 0) ? 1 : 0;
#pragma unroll
    for (int n = 0; n < 8; ++n) if (n != i0 && p[n] > p[i1]) i1 = n;
    pk[t * 2] = p[i0];
    pk[t * 2 + 1] = p[i1];
    idx[t * 2] = i0;
    idx[t * 2 + 1] = i1;
  }
}

// ---------------- deterministic per-expert compaction (1 block, 8 waves) ----------------
__global__ __launch_bounds__(512) void compact_k(const int* __restrict__ idx,
                                                 int* __restrict__ toklist,
                                                 int* __restrict__ ppos,
                                                 int* __restrict__ cnt) {
  int e = threadIdx.x >> 6;    // wave id = expert
  int lane = threadIdx.x & 63;
  int pos = 0;
  for (int base = 0; base < T; base += 64) {
    int t = base + lane;
    int i0 = idx[t * 2], i1 = idx[t * 2 + 1];
    bool sel = (i0 == e) || (i1 == e);
    unsigned long long m = __ballot(sel);
    int myoff = __popcll(m & ((1ull << lane) - 1ull));
    if (sel) {
      int p = pos + myoff;
      toklist[e * T + p] = t;
      ppos[t * 2 + ((i0 == e) ? 0 : 1)] = p;
    }
    pos += __popcll(m);
  }
  if (lane == 0) cnt[e] = pos;
}

// ---------------- bf16 MFMA GEMM over compact rows: C = act(A @ Wt^T + bias) ----------
// flags: 1 = relu, 2 = fp32 output, 4 = gather A rows via toklist.
__global__ __launch_bounds__(256) void moe_gemm_g(const __hip_bfloat16* __restrict__ A_,
                                                  const __hip_bfloat16* __restrict__ Wt_,
                                                  const float* __restrict__ bias_,
                                                  void* __restrict__ C_,
                                                  const int* __restrict__ toklist,
                                                  const int* __restrict__ cntp,
                                                  int N, int K,
                                                  long aB, long wB, long bB, long cB,
                                                  int flags) {
  const int e = blockIdx.z;
  const int cnt = cntp[e];
  const int m0 = blockIdx.y * 128;
  if (m0 >= cnt) return;
  const short* A = (const short*)A_ + ((flags & 4) ? 0 : (size_t)e * aB);
  const short* Wt = (const short*)Wt_ + (size_t)e * wB;
  const float* bias = bias_ + (size_t)e * bB;
  const int n0 = blockIdx.x * 64;
  __shared__ short As[128 * 64];  // XOR-swizzled 16B slots
  __shared__ short Bs[64 * 64];
  const int tid = threadIdx.x;
  const int lane = tid & 63, wid = tid >> 6;
  const int wr = wid >> 1, wc = wid & 1;
  const int lr = lane & 15, lg = lane >> 4;
  // per-thread staged rows: r(p) = p*32 + (tid>>3); resolve source row index once
  long arow_off[4];
#pragma unroll
  for (int p = 0; p < 4; ++p) {
    int row = p * 32 + (tid >> 3);
    int gr = m0 + row;
    int src;
    if (flags & 4) src = (gr < cnt) ? toklist[e * T + gr] : toklist[e * T];
    else src = gr;   // compact A: rows beyond cnt read in-bounds garbage (≤ T rows alloc)
    arow_off[p] = (size_t)src * K;
  }
  f4 acc[4][2];
#pragma unroll
  for (int fm = 0; fm < 4; ++fm)
#pragma unroll
    for (int fn = 0; fn < 2; ++fn) acc[fm][fn] = (f4){0.f, 0.f, 0.f, 0.f};

  const int slot = tid & 7;
  for (int kb = 0; kb < K; kb += 64) {
    __syncthreads();
#pragma unroll
    for (int p = 0; p < 4; ++p) {   // stage A: 128 rows x 64 bf16
      int row = p * 32 + (tid >> 3);
      s8 v = *(const s8*)(A + arow_off[p] + kb + slot * 8);
      *(s8*)&As[row * 64 + ((slot ^ (row & 7)) << 3)] = v;
    }
#pragma unroll
    for (int p = 0; p < 2; ++p) {   // stage B: 64 rows x 64 bf16
      int row = p * 32 + (tid >> 3);
      s8 v = *(const s8*)(Wt + (size_t)(n0 + row) * K + kb + slot * 8);
      *(s8*)&Bs[row * 64 + ((slot ^ (row & 7)) << 3)] = v;
    }
    __syncthreads();
#pragma unroll
    for (int kk = 0; kk < 64; kk += 32) {
      const int sb = (kk >> 3) + lg;
      s8 af[4], bf[2];
#pragma unroll
      for (int fm = 0; fm < 4; ++fm) {
        int row = wr * 64 + fm * 16 + lr;
        af[fm] = *(const s8*)&As[row * 64 + ((sb ^ (row & 7)) << 3)];
      }
#pragma unroll
      for (int fn = 0; fn < 2; ++fn) {
        int row = wc * 32 + fn * 16 + lr;
        bf[fn] = *(const s8*)&Bs[row * 64 + ((sb ^ (row & 7)) << 3)];
      }
#pragma unroll
      for (int fm = 0; fm < 4; ++fm)
#pragma unroll
        for (int fn = 0; fn < 2; ++fn)
          acc[fm][fn] = __builtin_amdgcn_mfma_f32_16x16x32_bf16(af[fm], bf[fn], acc[fm][fn], 0, 0, 0);
    }
  }
#pragma unroll
  for (int fm = 0; fm < 4; ++fm) {
#pragma unroll
    for (int fn = 0; fn < 2; ++fn) {
      int col = n0 + wc * 32 + fn * 16 + lr;
      int rowb = m0 + wr * 64 + fm * 16 + lg * 4;
      float bv = bias[col];
#pragma unroll
      for (int j = 0; j < 4; ++j) {
        if (rowb + j >= cnt) continue;
        float v = acc[fm][fn][j] + bv;
        if (flags & 1) v = fmaxf(v, 0.f);
        if (flags & 2)
          ((float*)C_)[(size_t)e * cB + (size_t)(rowb + j) * N + col] = v;
        else
          ((__hip_bfloat16*)C_)[(size_t)e * cB + (size_t)(rowb + j) * N + col] = __float2bfloat16(v);
      }
    }
  }
}

// ---------------- attention (RoPE on q fused) ----------------
__global__ __launch_bounds__(128) void attn_k(const float* __restrict__ q,
                                              const float* __restrict__ kk,
                                              const float* __restrict__ vv,
                                              float* __restrict__ ao) {
  int b = blockIdx.x / H, h = blockIdx.x % H;
  __shared__ float ks[64][32], vs[64][32];
  int tid = threadIdx.x;
  {
    int l = tid >> 1, hf = (tid & 1) * 16;
    const float4* ksrc = (const float4*)&kk[(size_t)(b * L + l) * E + h * HD + hf];
    const float4* vsrc = (const float4*)&vv[(size_t)(b * L + l) * E + h * HD + hf];
    float4* kdst = (float4*)&ks[l][hf];
    float4* vdst = (float4*)&vs[l][hf];
#pragma unroll
    for (int u = 0; u < 4; ++u) { kdst[u] = ksrc[u]; vdst[u] = vsrc[u]; }
  }
  __syncthreads();
  int s = tid;
  const float* qp = &q[(size_t)(b * S + s) * E + h * HD];
  float qv[32];
#pragma unroll
  for (int d = 0; d < 32; ++d) qv[d] = qp[d];
#pragma unroll
  for (int d = 0; d < 16; ++d) {
    float invf = exp2f(-(float)d * (13.287712379549449f / 16.0f));
    float ang = (float)s * invf;
    float sn, cs;
    __sincosf(ang, &sn, &cs);
    float x1 = qv[2 * d], x2 = qv[2 * d + 1];
    qv[2 * d] = x1 * cs - x2 * sn;
    qv[2 * d + 1] = x1 * sn + x2 * cs;
  }
  const float scale = 0.17677669529663687f;  // 1/sqrt(32)
  float mx = -1e30f;
  for (int l = 0; l < 64; ++l) {
    float dot = 0.f;
#pragma unroll
    for (int d = 0; d < 32; ++d) dot += qv[d] * ks[l][d];
    mx = fmaxf(mx, dot * scale);
  }
  float o[32];
#pragma unroll
  for (int d = 0; d < 32; ++d) o[d] = 0.f;
  float sum = 0.f;
  for (int l = 0; l < 64; ++l) {
    float dot = 0.f;
#pragma unroll
    for (int d = 0; d < 32; ++d) dot += qv[d] * ks[l][d];
    float wgt = __expf(dot * scale - mx);
    sum += wgt;
#pragma unroll
    for (int d = 0; d < 32; ++d) o[d] += wgt * vs[l][d];
  }
  float inv = 1.0f / sum;
  float* op = &ao[(size_t)(b * S + s) * E + h * HD];
#pragma unroll
  for (int d = 0; d < 32; ++d) op[d] = o[d] * inv;
}

// ---------------- combine (gather via ppos from compact eoc) ----------------
__global__ __launch_bounds__(256) void combine_k(const float* __restrict__ x1,
                                                 const float* __restrict__ eoc,
                                                 const float* __restrict__ pk,
                                                 const int* __restrict__ idx,
                                                 const int* __restrict__ ppos,
                                                 float* __restrict__ out) {
  int g = blockIdx.x * 256 + threadIdx.x;  // T*E = 196608
  int t = g / E;
  int e = g - t * E;
  int i0 = idx[t * 2], i1 = idx[t * 2 + 1];
  int p0 = ppos[t * 2], p1 = ppos[t * 2 + 1];
  out[g] = x1[g] + pk[t * 2] * eoc[((size_t)i0 * T + p0) * E + e]
                 + pk[t * 2 + 1] * eoc[((size_t)i1 * T + p1) * E + e];
}

extern "C" void kernel_launch(void* const* d_in, const int* in_sizes, int n_in,
                              void* d_out, int out_size, void* d_ws, size_t ws_size,
                              hipStream_t stream) {
  const float* x    = (const float*)d_in[0];
  const float* r1w  = (const float*)d_in[1];
  const float* r2w  = (const float*)d_in[2];
  const float* latW = (const float*)d_in[3];
  const float* latb = (const float*)d_in[4];
  const float* qW   = (const float*)d_in[5];
  const float* qb   = (const float*)d_in[6];
  const float* kW   = (const float*)d_in[7];
  const float* kb   = (const float*)d_in[8];
  const float* vW   = (const float*)d_in[9];
  const float* vb   = (const float*)d_in[10];
  const float* oW   = (const float*)d_in[11];
  const float* ob   = (const float*)d_in[12];
  const float* rW   = (const float*)d_in[13];
  const float* rb   = (const float*)d_in[14];
  const float* e1W  = (const float*)d_in[15];
  const float* e1b  = (const float*)d_in[16];
  const float* swW  = (const float*)d_in[17];
  const float* swb  = (const float*)d_in[18];
  const float* e2W  = (const float*)d_in[19];
  const float* e2b  = (const float*)d_in[20];
  float* out = (float*)d_out;

  float* ws = (float*)d_ws;
  float* xn1  = ws;                     // 196608 f32
  float* lat  = ws + 196608;            // 98304
  float* qbuf = ws + 294912;            // 196608
  float* kbuf = ws + 491520;            // 98304
  float* vbuf = ws + 589824;            // 98304
  float* ao   = ws + 688128;            // 196608
  float* x1   = ws + 884736;            // 196608
  float* pk   = ws + 1277952;           // 2048
  int*   idx  = (int*)(ws + 1280000);   // 2048 ints
  int*   toklist = (int*)(ws + 1282048);  // 8192 ints
  int*   ppos    = (int*)(ws + 1290240);  // 2048 ints
  int*   cnt     = (int*)(ws + 1292288);  // 8 ints
  __hip_bfloat16* hb    = (__hip_bfloat16*)(ws + 1294336);  // 196608 bf16
  __hip_bfloat16* e1Wt  = (__hip_bfloat16*)(ws + 1392640);  // 8*768*192 bf16
  __hip_bfloat16* swWt  = (__hip_bfloat16*)(ws + 1982464);  // 8*768*768 bf16
  __hip_bfloat16* e2Wt  = (__hip_bfloat16*)(ws + 4341760);  // 8*192*768 bf16
  __hip_bfloat16* t1    = (__hip_bfloat16*)(ws + 4931584);  // 8*1024*768 bf16
  __hip_bfloat16* t2    = (__hip_bfloat16*)(ws + 8077312);  // 8*1024*768 bf16
  float* eoc  = ws + 11223040;          // 8*1024*192 f32
  float* part = ws + 12795904;          // 64*98304 f32

  // 0) expert weight transpose + bf16 convert
  tconv_k<<<dim3(E / 32, ED / 32, NEXP), 256, 0, stream>>>(e1W, e1Wt, E, ED);
  tconv_k<<<dim3(ED / 32, ED / 32, NEXP), 256, 0, stream>>>(swW, swWt, ED, ED);
  tconv_k<<<dim3(ED / 32, E / 32, NEXP), 256, 0, stream>>>(e2W, e2Wt, ED, E);

  // 1) rmsnorm1
  rmsnorm_k<<<T, 64, 0, stream>>>(x, r1w, xn1);
  // 2) latent = xn1 @ latW + latb
  lat_partial_k<<<dim3(12, SPLITS), 256, 0, stream>>>(xn1, latW, part);
  lat_reduce_k<<<(8 * LE) / 256, 256, 0, stream>>>(part, latb, lat);
  // 3) q,k,v projections fused
  qkv_k<<<dim3(3, 16, 3), 256, 0, stream>>>(xn1, lat, qW, qb, kW, kb, vW, vb,
                                            qbuf, kbuf, vbuf);
  // 4) attention (rope fused)
  attn_k<<<B * H, 128, 0, stream>>>(qbuf, kbuf, vbuf, ao);
  // 5) o-proj + residual
  gemm_k<<<dim3(3, 16), 256, 0, stream>>>(ao, oW, ob, x, x1, T, E, E, 2);
  // 6) rmsnorm2 + router fused
  router_rms_k<<<T, 64, 0, stream>>>(x1, r2w, rW, rb, hb, pk, idx);
  // 7) deterministic compaction
  compact_k<<<1, 512, 0, stream>>>(idx, toklist, ppos, cnt);
  // 8) MoE top-2 stages (compact row space; worst-case grid, early exit)
  moe_gemm_g<<<dim3(ED / 64, 8, NEXP), 256, 0, stream>>>(
      hb, e1Wt, e1b, t1, toklist, cnt, ED, E, 0, (long)ED * E, ED, (long)T * ED, 4);
  moe_gemm_g<<<dim3(ED / 64, 8, NEXP), 256, 0, stream>>>(
      t1, swWt, swb, t2, toklist, cnt, ED, ED, (long)T * ED, (long)ED * ED, ED, (long)T * ED, 1);
  moe_gemm_g<<<dim3(E / 64, 8, NEXP), 256, 0, stream>>>(
      t2, e2Wt, e2b, eoc, toklist, cnt, E, ED, (long)T * ED, (long)E * ED, E, (long)T * E, 2);
  // 9) combine
  combine_k<<<(T * E) / 256, 256, 0, stream>>>(x1, eoc, pk, idx, ppos, out);
}

// Round 8
// 322.329 us; speedup vs baseline: 1.8887x; 1.0559x over previous
//
#include <hip/hip_runtime.h>
#include <hip/hip_bf16.h>
#include <math.h>

#define B 8
#define S 128
#define E 192
#define H 6
#define HD 32
#define L 64
#define NEXP 8
#define ED 768
#define T (B*S)     // 1024
#define SE (S*E)    // 24576
#define LE (L*E)    // 12288

#define SPLITS 64
#define ISPAN 384   // 24576/64
#define CHUNK 128

using s8 = __attribute__((ext_vector_type(8))) short;   // 8 bf16 (4 VGPRs)
using f4 = __attribute__((ext_vector_type(4))) float;   // 4 fp32

// ---------------- RMSNorm1: fp32 out (lat GEMM) + bf16 out (q proj) ----------------
__global__ __launch_bounds__(64) void rmsnorm_bf_k(const float* __restrict__ x,
                                                   const float* __restrict__ w,
                                                   float* __restrict__ y,
                                                   __hip_bfloat16* __restrict__ yb) {
  int row = blockIdx.x;
  int lane = threadIdx.x;
  const float* xr = x + (size_t)row * E;
  float v0 = xr[lane], v1 = xr[lane + 64], v2 = xr[lane + 128];
  float s = v0 * v0 + v1 * v1 + v2 * v2;
#pragma unroll
  for (int off = 32; off > 0; off >>= 1) s += __shfl_xor(s, off);
  float inv = rsqrtf(s * (1.0f / E) + 1e-5f);
  float r0 = v0 * inv * w[lane];
  float r1 = v1 * inv * w[lane + 64];
  float r2 = v2 * inv * w[lane + 128];
  float* yr = y + (size_t)row * E;
  __hip_bfloat16* yrb = yb + (size_t)row * E;
  yr[lane] = r0; yr[lane + 64] = r1; yr[lane + 128] = r2;
  yrb[lane] = __float2bfloat16(r0);
  yrb[lane + 64] = __float2bfloat16(r1);
  yrb[lane + 128] = __float2bfloat16(r2);
}

// ---------------- latent GEMM: partials over i-splits ----------------
__global__ __launch_bounds__(256) void lat_partial_k(const float* __restrict__ xn,
                                                     const float* __restrict__ latW,
                                                     float* __restrict__ part) {
  const int tid = threadIdx.x;
  const int j = blockIdx.x * 1024 + tid * 4;
  const int i0 = blockIdx.y * ISPAN;
  __shared__ float xs[CHUNK][8];
  f4 acc[8];
#pragma unroll
  for (int b = 0; b < 8; ++b) acc[b] = (f4){0.f, 0.f, 0.f, 0.f};
  for (int c = 0; c < ISPAN; c += CHUNK) {
    float* xsf = (float*)xs;
    __syncthreads();
    for (int l = tid; l < CHUNK * 8; l += 256) {
      int ii = l >> 3, b = l & 7;
      xsf[l] = xn[(size_t)b * SE + i0 + c + ii];
    }
    __syncthreads();
#pragma unroll 8
    for (int ii = 0; ii < CHUNK; ++ii) {
      const f4 w = __builtin_nontemporal_load(
          (const f4*)&latW[(size_t)(i0 + c + ii) * LE + j]);
#pragma unroll
      for (int b = 0; b < 8; ++b) {
        float xv = xs[ii][b];
        acc[b][0] += xv * w[0];
        acc[b][1] += xv * w[1];
        acc[b][2] += xv * w[2];
        acc[b][3] += xv * w[3];
      }
    }
  }
#pragma unroll
  for (int b = 0; b < 8; ++b)
    *(f4*)&part[((size_t)blockIdx.y * 8 + b) * LE + j] = acc[b];
}

// reduce partials -> latent, write bf16 (consumed only by k/v MFMA projections)
__global__ __launch_bounds__(256) void lat_reduce_k(const float* __restrict__ part,
                                                    const float* __restrict__ latb,
                                                    __hip_bfloat16* __restrict__ lat16) {
  int g = blockIdx.x * 256 + threadIdx.x;  // < 8*LE
  int b = g / LE, j = g - b * LE;
  float s = latb[j];
  for (int sp = 0; sp < SPLITS; ++sp) s += part[((size_t)sp * 8 + b) * LE + j];
  lat16[g] = __float2bfloat16(s);
}

// ---------------- transpose+bf16 for the four E x E weights (z: q,k,v,o) -------------
__global__ __launch_bounds__(256) void tconv4_k(const float* __restrict__ qW,
                                                const float* __restrict__ kW,
                                                const float* __restrict__ vW,
                                                const float* __restrict__ oW,
                                                __hip_bfloat16* __restrict__ qWt,
                                                __hip_bfloat16* __restrict__ kWt,
                                                __hip_bfloat16* __restrict__ vWt,
                                                __hip_bfloat16* __restrict__ oWt) {
  const int z = blockIdx.z;
  const float* in = (z == 0) ? qW : (z == 1) ? kW : (z == 2) ? vW : oW;
  __hip_bfloat16* out = (z == 0) ? qWt : (z == 1) ? kWt : (z == 2) ? vWt : oWt;
  __shared__ float tile[32][33];
  int tx = threadIdx.x & 31, r8 = threadIdx.x >> 5;
  int k0 = blockIdx.x * 32, n0 = blockIdx.y * 32;
#pragma unroll
  for (int i = 0; i < 4; ++i)
    tile[r8 + 8 * i][tx] = in[(size_t)(k0 + r8 + 8 * i) * E + n0 + tx];
  __syncthreads();
#pragma unroll
  for (int i = 0; i < 4; ++i) {
    int nr = r8 + 8 * i;
    out[(size_t)(n0 + nr) * E + k0 + tx] = __float2bfloat16(tile[tx][nr]);
  }
}

// ---------------- expert weight transpose + fp32->bf16 ----------------
__global__ __launch_bounds__(256) void tconv_k(const float* __restrict__ in,
                                               __hip_bfloat16* __restrict__ out,
                                               int K, int N) {
  const int e = blockIdx.z;
  in += (size_t)e * K * N;
  out += (size_t)e * N * K;
  __shared__ float tile[32][33];
  int tx = threadIdx.x & 31, r8 = threadIdx.x >> 5;
  int k0 = blockIdx.x * 32, n0 = blockIdx.y * 32;
#pragma unroll
  for (int i = 0; i < 4; ++i)
    tile[r8 + 8 * i][tx] = in[(size_t)(k0 + r8 + 8 * i) * N + n0 + tx];
  __syncthreads();
#pragma unroll
  for (int i = 0; i < 4; ++i) {
    int nr = r8 + 8 * i;
    out[(size_t)(n0 + nr) * K + k0 + tx] = __float2bfloat16(tile[tx][nr]);
  }
}

// ---------------- q/k/v projections via bf16 MFMA, one dispatch ----------------
// z=0: q = xnb @ qWt^T (M=1024); z=1: k = lat16 @ kWt^T (M=512); z=2: v (M=512).
// 128x64 tile, K=192, fp32 output.
__global__ __launch_bounds__(256) void qkv_mm_k(const __hip_bfloat16* __restrict__ xnb,
                                                const __hip_bfloat16* __restrict__ lat16,
                                                const __hip_bfloat16* __restrict__ qWt,
                                                const __hip_bfloat16* __restrict__ kWt,
                                                const __hip_bfloat16* __restrict__ vWt,
                                                const float* __restrict__ qb,
                                                const float* __restrict__ kb,
                                                const float* __restrict__ vb,
                                                float* __restrict__ qo,
                                                float* __restrict__ ko,
                                                float* __restrict__ vo) {
  const int z = blockIdx.z;
  const int M = (z == 0) ? T : (B * L);
  const int m0 = blockIdx.y * 128;
  if (m0 >= M) return;
  const short* A = (const short*)((z == 0) ? xnb : lat16);
  const short* Wt = (const short*)((z == 0) ? qWt : (z == 1) ? kWt : vWt);
  const float* bias = (z == 0) ? qb : (z == 1) ? kb : vb;
  float* C = (z == 0) ? qo : (z == 1) ? ko : vo;
  const int n0 = blockIdx.x * 64;
  __shared__ short As[128 * 64];
  __shared__ short Bs[64 * 64];
  const int tid = threadIdx.x;
  const int lane = tid & 63, wid = tid >> 6;
  const int wr = wid >> 1, wc = wid & 1;
  const int lr = lane & 15, lg = lane >> 4;
  const int slot = tid & 7;
  f4 acc[4][2];
#pragma unroll
  for (int fm = 0; fm < 4; ++fm)
#pragma unroll
    for (int fn = 0; fn < 2; ++fn) acc[fm][fn] = (f4){0.f, 0.f, 0.f, 0.f};
  for (int kb2 = 0; kb2 < E; kb2 += 64) {
    __syncthreads();
#pragma unroll
    for (int p = 0; p < 4; ++p) {
      int row = p * 32 + (tid >> 3);
      s8 v = *(const s8*)(A + (size_t)(m0 + row) * E + kb2 + slot * 8);
      *(s8*)&As[row * 64 + ((slot ^ (row & 7)) << 3)] = v;
    }
#pragma unroll
    for (int p = 0; p < 2; ++p) {
      int row = p * 32 + (tid >> 3);
      s8 v = *(const s8*)(Wt + (size_t)(n0 + row) * E + kb2 + slot * 8);
      *(s8*)&Bs[row * 64 + ((slot ^ (row & 7)) << 3)] = v;
    }
    __syncthreads();
#pragma unroll
    for (int kk = 0; kk < 64; kk += 32) {
      const int sb = (kk >> 3) + lg;
      s8 af[4], bf[2];
#pragma unroll
      for (int fm = 0; fm < 4; ++fm) {
        int row = wr * 64 + fm * 16 + lr;
        af[fm] = *(const s8*)&As[row * 64 + ((sb ^ (row & 7)) << 3)];
      }
#pragma unroll
      for (int fn = 0; fn < 2; ++fn) {
        int row = wc * 32 + fn * 16 + lr;
        bf[fn] = *(const s8*)&Bs[row * 64 + ((sb ^ (row & 7)) << 3)];
      }
#pragma unroll
      for (int fm = 0; fm < 4; ++fm)
#pragma unroll
        for (int fn = 0; fn < 2; ++fn)
          acc[fm][fn] = __builtin_amdgcn_mfma_f32_16x16x32_bf16(af[fm], bf[fn], acc[fm][fn], 0, 0, 0);
    }
  }
#pragma unroll
  for (int fm = 0; fm < 4; ++fm)
#pragma unroll
    for (int fn = 0; fn < 2; ++fn) {
      int col = n0 + wc * 32 + fn * 16 + lr;
      int rowb = m0 + wr * 64 + fm * 16 + lg * 4;
      float bv = bias[col];
#pragma unroll
      for (int j = 0; j < 4; ++j)
        C[(size_t)(rowb + j) * E + col] = acc[fm][fn][j] + bv;
    }
}

// ---------------- o-proj via bf16 MFMA, residual fused: x1 = ao@oWt^T + ob + x -------
__global__ __launch_bounds__(256) void oproj_mm_k(const __hip_bfloat16* __restrict__ aob,
                                                  const __hip_bfloat16* __restrict__ oWt,
                                                  const float* __restrict__ ob,
                                                  const float* __restrict__ x,
                                                  float* __restrict__ x1) {
  const int m0 = blockIdx.y * 128;
  const int n0 = blockIdx.x * 64;
  const short* A = (const short*)aob;
  const short* Wt = (const short*)oWt;
  __shared__ short As[128 * 64];
  __shared__ short Bs[64 * 64];
  const int tid = threadIdx.x;
  const int lane = tid & 63, wid = tid >> 6;
  const int wr = wid >> 1, wc = wid & 1;
  const int lr = lane & 15, lg = lane >> 4;
  const int slot = tid & 7;
  f4 acc[4][2];
#pragma unroll
  for (int fm = 0; fm < 4; ++fm)
#pragma unroll
    for (int fn = 0; fn < 2; ++fn) acc[fm][fn] = (f4){0.f, 0.f, 0.f, 0.f};
  for (int kb2 = 0; kb2 < E; kb2 += 64) {
    __syncthreads();
#pragma unroll
    for (int p = 0; p < 4; ++p) {
      int row = p * 32 + (tid >> 3);
      s8 v = *(const s8*)(A + (size_t)(m0 + row) * E + kb2 + slot * 8);
      *(s8*)&As[row * 64 + ((slot ^ (row & 7)) << 3)] = v;
    }
#pragma unroll
    for (int p = 0; p < 2; ++p) {
      int row = p * 32 + (tid >> 3);
      s8 v = *(const s8*)(Wt + (size_t)(n0 + row) * E + kb2 + slot * 8);
      *(s8*)&Bs[row * 64 + ((slot ^ (row & 7)) << 3)] = v;
    }
    __syncthreads();
#pragma unroll
    for (int kk = 0; kk < 64; kk += 32) {
      const int sb = (kk >> 3) + lg;
      s8 af[4], bf[2];
#pragma unroll
      for (int fm = 0; fm < 4; ++fm) {
        int row = wr * 64 + fm * 16 + lr;
        af[fm] = *(const s8*)&As[row * 64 + ((sb ^ (row & 7)) << 3)];
      }
#pragma unroll
      for (int fn = 0; fn < 2; ++fn) {
        int row = wc * 32 + fn * 16 + lr;
        bf[fn] = *(const s8*)&Bs[row * 64 + ((sb ^ (row & 7)) << 3)];
      }
#pragma unroll
      for (int fm = 0; fm < 4; ++fm)
#pragma unroll
        for (int fn = 0; fn < 2; ++fn)
          acc[fm][fn] = __builtin_amdgcn_mfma_f32_16x16x32_bf16(af[fm], bf[fn], acc[fm][fn], 0, 0, 0);
    }
  }
#pragma unroll
  for (int fm = 0; fm < 4; ++fm)
#pragma unroll
    for (int fn = 0; fn < 2; ++fn) {
      int col = n0 + wc * 32 + fn * 16 + lr;
      int rowb = m0 + wr * 64 + fm * 16 + lg * 4;
      float bv = ob[col];
#pragma unroll
      for (int j = 0; j < 4; ++j) {
        size_t off = (size_t)(rowb + j) * E + col;
        x1[off] = acc[fm][fn][j] + bv + x[off];
      }
    }
}

// ---------------- fused rmsnorm2 + router ----------------
__global__ __launch_bounds__(64) void router_rms_k(const float* __restrict__ x1,
                                                   const float* __restrict__ w,
                                                   const float* __restrict__ rW,
                                                   const float* __restrict__ rb,
                                                   __hip_bfloat16* __restrict__ hb,
                                                   float* __restrict__ pk,
                                                   int* __restrict__ idx) {
  int t = blockIdx.x;
  int lane = threadIdx.x;
  const float* xr = x1 + (size_t)t * E;
  float v0 = xr[lane], v1 = xr[lane + 64], v2 = xr[lane + 128];
  float s = v0 * v0 + v1 * v1 + v2 * v2;
#pragma unroll
  for (int off = 32; off > 0; off >>= 1) s += __shfl_xor(s, off);
  float inv = rsqrtf(s * (1.0f / E) + 1e-5f);
  float r0 = v0 * inv * w[lane];
  float r1 = v1 * inv * w[lane + 64];
  float r2 = v2 * inv * w[lane + 128];
  __hip_bfloat16* yrb = hb + (size_t)t * E;
  yrb[lane] = __float2bfloat16(r0);
  yrb[lane + 64] = __float2bfloat16(r1);
  yrb[lane + 128] = __float2bfloat16(r2);
  float lg[8];
#pragma unroll
  for (int n = 0; n < 8; ++n)
    lg[n] = r0 * rW[lane * 8 + n] + r1 * rW[(lane + 64) * 8 + n] + r2 * rW[(lane + 128) * 8 + n];
#pragma unroll
  for (int n = 0; n < 8; ++n)
#pragma unroll
    for (int off = 32; off > 0; off >>= 1) lg[n] += __shfl_xor(lg[n], off);
  if (lane == 0) {
#pragma unroll
    for (int n = 0; n < 8; ++n) lg[n] += rb[n];
    float mx = lg[0];
#pragma unroll
    for (int n = 1; n < 8; ++n) mx = fmaxf(mx, lg[n]);
    float p[8], sum = 0.f;
#pragma unroll
    for (int n = 0; n < 8; ++n) { p[n] = __expf(lg[n] - mx); sum += p[n]; }
    float isum = 1.f / sum;
#pragma unroll
    for (int n = 0; n < 8; ++n) p[n] *= isum;
    int i0 = 0;
#pragma unroll
    for (int n = 1; n < 8; ++n) if (p[n] > p[i0]) i0 = n;
    int i1 = (i0 == 0) ? 1 : 0;
#pragma unroll
    for (int n = 0; n < 8; ++n) if (n != i0 && p[n] > p[i1]) i1 = n;
    pk[t * 2] = p[i0];
    pk[t * 2 + 1] = p[i1];
    idx[t * 2] = i0;
    idx[t * 2 + 1] = i1;
  }
}

// ---------------- deterministic per-expert compaction (1 block, 8 waves) -------------
__global__ __launch_bounds__(512) void compact_k(const int* __restrict__ idx,
                                                 int* __restrict__ toklist,
                                                 int* __restrict__ ppos,
                                                 int* __restrict__ cnt) {
  int e = threadIdx.x >> 6;
  int lane = threadIdx.x & 63;
  int pos = 0;
  for (int base = 0; base < T; base += 64) {
    int t = base + lane;
    int i0 = idx[t * 2], i1 = idx[t * 2 + 1];
    bool sel = (i0 == e) || (i1 == e);
    unsigned long long m = __ballot(sel);
    int myoff = __popcll(m & ((1ull << lane) - 1ull));
    if (sel) {
      int p = pos + myoff;
      toklist[e * T + p] = t;
      ppos[t * 2 + ((i0 == e) ? 0 : 1)] = p;
    }
    pos += __popcll(m);
  }
  if (lane == 0) cnt[e] = pos;
}

// ---------------- bf16 MFMA GEMM over compact rows ----------------
// flags: 1 = relu, 2 = fp32 output, 4 = gather A rows via toklist.
__global__ __launch_bounds__(256) void moe_gemm_g(const __hip_bfloat16* __restrict__ A_,
                                                  const __hip_bfloat16* __restrict__ Wt_,
                                                  const float* __restrict__ bias_,
                                                  void* __restrict__ C_,
                                                  const int* __restrict__ toklist,
                                                  const int* __restrict__ cntp,
                                                  int N, int K,
                                                  long aB, long wB, long bB, long cB,
                                                  int flags) {
  const int e = blockIdx.z;
  const int cnt = cntp[e];
  const int m0 = blockIdx.y * 128;
  if (m0 >= cnt) return;
  const short* A = (const short*)A_ + ((flags & 4) ? 0 : (size_t)e * aB);
  const short* Wt = (const short*)Wt_ + (size_t)e * wB;
  const float* bias = bias_ + (size_t)e * bB;
  const int n0 = blockIdx.x * 64;
  __shared__ short As[128 * 64];
  __shared__ short Bs[64 * 64];
  const int tid = threadIdx.x;
  const int lane = tid & 63, wid = tid >> 6;
  const int wr = wid >> 1, wc = wid & 1;
  const int lr = lane & 15, lg = lane >> 4;
  long arow_off[4];
#pragma unroll
  for (int p = 0; p < 4; ++p) {
    int row = p * 32 + (tid >> 3);
    int gr = m0 + row;
    int src;
    if (flags & 4) src = (gr < cnt) ? toklist[e * T + gr] : toklist[e * T];
    else src = gr;
    arow_off[p] = (size_t)src * K;
  }
  f4 acc[4][2];
#pragma unroll
  for (int fm = 0; fm < 4; ++fm)
#pragma unroll
    for (int fn = 0; fn < 2; ++fn) acc[fm][fn] = (f4){0.f, 0.f, 0.f, 0.f};
  const int slot = tid & 7;
  for (int kb = 0; kb < K; kb += 64) {
    __syncthreads();
#pragma unroll
    for (int p = 0; p < 4; ++p) {
      int row = p * 32 + (tid >> 3);
      s8 v = *(const s8*)(A + arow_off[p] + kb + slot * 8);
      *(s8*)&As[row * 64 + ((slot ^ (row & 7)) << 3)] = v;
    }
#pragma unroll
    for (int p = 0; p < 2; ++p) {
      int row = p * 32 + (tid >> 3);
      s8 v = *(const s8*)(Wt + (size_t)(n0 + row) * K + kb + slot * 8);
      *(s8*)&Bs[row * 64 + ((slot ^ (row & 7)) << 3)] = v;
    }
    __syncthreads();
#pragma unroll
    for (int kk = 0; kk < 64; kk += 32) {
      const int sb = (kk >> 3) + lg;
      s8 af[4], bf[2];
#pragma unroll
      for (int fm = 0; fm < 4; ++fm) {
        int row = wr * 64 + fm * 16 + lr;
        af[fm] = *(const s8*)&As[row * 64 + ((sb ^ (row & 7)) << 3)];
      }
#pragma unroll
      for (int fn = 0; fn < 2; ++fn) {
        int row = wc * 32 + fn * 16 + lr;
        bf[fn] = *(const s8*)&Bs[row * 64 + ((sb ^ (row & 7)) << 3)];
      }
#pragma unroll
      for (int fm = 0; fm < 4; ++fm)
#pragma unroll
        for (int fn = 0; fn < 2; ++fn)
          acc[fm][fn] = __builtin_amdgcn_mfma_f32_16x16x32_bf16(af[fm], bf[fn], acc[fm][fn], 0, 0, 0);
    }
  }
#pragma unroll
  for (int fm = 0; fm < 4; ++fm) {
#pragma unroll
    for (int fn = 0; fn < 2; ++fn) {
      int col = n0 + wc * 32 + fn * 16 + lr;
      int rowb = m0 + wr * 64 + fm * 16 + lg * 4;
      float bv = bias[col];
#pragma unroll
      for (int j = 0; j < 4; ++j) {
        if (rowb + j >= cnt) continue;
        float v = acc[fm][fn][j] + bv;
        if (flags & 1) v = fmaxf(v, 0.f);
        if (flags & 2)
          ((float*)C_)[(size_t)e * cB + (size_t)(rowb + j) * N + col] = v;
        else
          ((__hip_bfloat16*)C_)[(size_t)e * cB + (size_t)(rowb + j) * N + col] = __float2bfloat16(v);
      }
    }
  }
}

// ---------------- attention (RoPE fused), bf16 output ----------------
__global__ __launch_bounds__(128) void attn_k(const float* __restrict__ q,
                                              const float* __restrict__ kk,
                                              const float* __restrict__ vv,
                                              __hip_bfloat16* __restrict__ aob) {
  int b = blockIdx.x / H, h = blockIdx.x % H;
  __shared__ float ks[64][32], vs[64][32];
  int tid = threadIdx.x;
  {
    int l = tid >> 1, hf = (tid & 1) * 16;
    const float4* ksrc = (const float4*)&kk[(size_t)(b * L + l) * E + h * HD + hf];
    const float4* vsrc = (const float4*)&vv[(size_t)(b * L + l) * E + h * HD + hf];
    float4* kdst = (float4*)&ks[l][hf];
    float4* vdst = (float4*)&vs[l][hf];
#pragma unroll
    for (int u = 0; u < 4; ++u) { kdst[u] = ksrc[u]; vdst[u] = vsrc[u]; }
  }
  __syncthreads();
  int s = tid;
  const float* qp = &q[(size_t)(b * S + s) * E + h * HD];
  float qv[32];
#pragma unroll
  for (int d = 0; d < 32; ++d) qv[d] = qp[d];
#pragma unroll
  for (int d = 0; d < 16; ++d) {
    float invf = exp2f(-(float)d * (13.287712379549449f / 16.0f));
    float ang = (float)s * invf;
    float sn, cs;
    __sincosf(ang, &sn, &cs);
    float x1 = qv[2 * d], x2 = qv[2 * d + 1];
    qv[2 * d] = x1 * cs - x2 * sn;
    qv[2 * d + 1] = x1 * sn + x2 * cs;
  }
  const float scale = 0.17677669529663687f;  // 1/sqrt(32)
  float mx = -1e30f;
  for (int l = 0; l < 64; ++l) {
    float dot = 0.f;
#pragma unroll
    for (int d = 0; d < 32; ++d) dot += qv[d] * ks[l][d];
    mx = fmaxf(mx, dot * scale);
  }
  float o[32];
#pragma unroll
  for (int d = 0; d < 32; ++d) o[d] = 0.f;
  float sum = 0.f;
  for (int l = 0; l < 64; ++l) {
    float dot = 0.f;
#pragma unroll
    for (int d = 0; d < 32; ++d) dot += qv[d] * ks[l][d];
    float wgt = __expf(dot * scale - mx);
    sum += wgt;
#pragma unroll
    for (int d = 0; d < 32; ++d) o[d] += wgt * vs[l][d];
  }
  float inv = 1.0f / sum;
  __hip_bfloat16* op = &aob[(size_t)(b * S + s) * E + h * HD];
#pragma unroll
  for (int d = 0; d < 32; ++d) op[d] = __float2bfloat16(o[d] * inv);
}

// ---------------- combine (gather via ppos from compact eoc) ----------------
__global__ __launch_bounds__(256) void combine_k(const float* __restrict__ x1,
                                                 const float* __restrict__ eoc,
                                                 const float* __restrict__ pk,
                                                 const int* __restrict__ idx,
                                                 const int* __restrict__ ppos,
                                                 float* __restrict__ out) {
  int g = blockIdx.x * 256 + threadIdx.x;  // T*E = 196608
  int t = g / E;
  int e = g - t * E;
  int i0 = idx[t * 2], i1 = idx[t * 2 + 1];
  int p0 = ppos[t * 2], p1 = ppos[t * 2 + 1];
  out[g] = x1[g] + pk[t * 2] * eoc[((size_t)i0 * T + p0) * E + e]
                 + pk[t * 2 + 1] * eoc[((size_t)i1 * T + p1) * E + e];
}

extern "C" void kernel_launch(void* const* d_in, const int* in_sizes, int n_in,
                              void* d_out, int out_size, void* d_ws, size_t ws_size,
                              hipStream_t stream) {
  const float* x    = (const float*)d_in[0];
  const float* r1w  = (const float*)d_in[1];
  const float* r2w  = (const float*)d_in[2];
  const float* latW = (const float*)d_in[3];
  const float* latb = (const float*)d_in[4];
  const float* qW   = (const float*)d_in[5];
  const float* qb   = (const float*)d_in[6];
  const float* kW   = (const float*)d_in[7];
  const float* kb   = (const float*)d_in[8];
  const float* vW   = (const float*)d_in[9];
  const float* vb   = (const float*)d_in[10];
  const float* oW   = (const float*)d_in[11];
  const float* ob   = (const float*)d_in[12];
  const float* rW   = (const float*)d_in[13];
  const float* rb   = (const float*)d_in[14];
  const float* e1W  = (const float*)d_in[15];
  const float* e1b  = (const float*)d_in[16];
  const float* swW  = (const float*)d_in[17];
  const float* swb  = (const float*)d_in[18];
  const float* e2W  = (const float*)d_in[19];
  const float* e2b  = (const float*)d_in[20];
  float* out = (float*)d_out;

  float* ws = (float*)d_ws;
  float* xn1  = ws;                                         // 196608 f32
  __hip_bfloat16* xnb   = (__hip_bfloat16*)(ws + 196608);   // 196608 bf16
  __hip_bfloat16* lat16 = (__hip_bfloat16*)(ws + 294912);   // 98304 bf16
  float* qbuf = ws + 344064;            // 196608 f32
  float* kbuf = ws + 540672;            // 98304
  float* vbuf = ws + 638976;            // 98304
  __hip_bfloat16* aob   = (__hip_bfloat16*)(ws + 737280);   // 196608 bf16
  float* x1   = ws + 835584;            // 196608
  float* pk   = ws + 1032192;           // 2048
  int*   idx  = (int*)(ws + 1034240);   // 2048
  int*   toklist = (int*)(ws + 1036288);  // 8192
  int*   ppos    = (int*)(ws + 1044480);  // 2048
  int*   cnt     = (int*)(ws + 1046528);  // 8 (pad 256)
  __hip_bfloat16* qWt = (__hip_bfloat16*)(ws + 1046784);    // 36864 bf16
  __hip_bfloat16* kWt = (__hip_bfloat16*)(ws + 1065216);
  __hip_bfloat16* vWt = (__hip_bfloat16*)(ws + 1083648);
  __hip_bfloat16* oWt = (__hip_bfloat16*)(ws + 1102080);
  __hip_bfloat16* hb    = (__hip_bfloat16*)(ws + 1120512);  // 196608 bf16
  __hip_bfloat16* e1Wt  = (__hip_bfloat16*)(ws + 1218816);  // 1179648 bf16
  __hip_bfloat16* swWt  = (__hip_bfloat16*)(ws + 1808640);  // 4718592 bf16
  __hip_bfloat16* e2Wt  = (__hip_bfloat16*)(ws + 4167936);  // 1179648 bf16
  __hip_bfloat16* t1    = (__hip_bfloat16*)(ws + 4757760);  // 6291456 bf16
  __hip_bfloat16* t2    = (__hip_bfloat16*)(ws + 7903488);  // 6291456 bf16
  float* eoc  = ws + 11049216;          // 1572864 f32
  float* part = ws + 12622080;          // 6291456 f32

  // 0) weight transposes + bf16 conversion
  tconv_k<<<dim3(E / 32, ED / 32, NEXP), 256, 0, stream>>>(e1W, e1Wt, E, ED);
  tconv_k<<<dim3(ED / 32, ED / 32, NEXP), 256, 0, stream>>>(swW, swWt, ED, ED);
  tconv_k<<<dim3(ED / 32, E / 32, NEXP), 256, 0, stream>>>(e2W, e2Wt, ED, E);
  tconv4_k<<<dim3(6, 6, 4), 256, 0, stream>>>(qW, kW, vW, oW, qWt, kWt, vWt, oWt);

  // 1) rmsnorm1 (fp32 + bf16)
  rmsnorm_bf_k<<<T, 64, 0, stream>>>(x, r1w, xn1, xnb);
  // 2) latent = xn1 @ latW + latb (fp32 stream, bf16 out)
  lat_partial_k<<<dim3(12, SPLITS), 256, 0, stream>>>(xn1, latW, part);
  lat_reduce_k<<<(8 * LE) / 256, 256, 0, stream>>>(part, latb, lat16);
  // 3) q,k,v projections via MFMA, one dispatch
  qkv_mm_k<<<dim3(3, 8, 3), 256, 0, stream>>>(xnb, lat16, qWt, kWt, vWt,
                                              qb, kb, vb, qbuf, kbuf, vbuf);
  // 4) attention (rope fused) -> bf16
  attn_k<<<B * H, 128, 0, stream>>>(qbuf, kbuf, vbuf, aob);
  // 5) o-proj + residual via MFMA
  oproj_mm_k<<<dim3(3, 8), 256, 0, stream>>>(aob, oWt, ob, x, x1);
  // 6) rmsnorm2 + router fused
  router_rms_k<<<T, 64, 0, stream>>>(x1, r2w, rW, rb, hb, pk, idx);
  // 7) deterministic compaction
  compact_k<<<1, 512, 0, stream>>>(idx, toklist, ppos, cnt);
  // 8) MoE top-2 stages (compact rows, early exit)
  moe_gemm_g<<<dim3(ED / 64, 8, NEXP), 256, 0, stream>>>(
      hb, e1Wt, e1b, t1, toklist, cnt, ED, E, 0, (long)ED * E, ED, (long)T * ED, 4);
  moe_gemm_g<<<dim3(ED / 64, 8, NEXP), 256, 0, stream>>>(
      t1, swWt, swb, t2, toklist, cnt, ED, ED, (long)T * ED, (long)ED * ED, ED, (long)T * ED, 1);
  moe_gemm_g<<<dim3(E / 64, 8, NEXP), 256, 0, stream>>>(
      t2, e2Wt, e2b, eoc, toklist, cnt, E, ED, (long)T * ED, (long)E * ED, E, (long)T * E, 2);
  // 9) combine
  combine_k<<<(T * E) / 256, 256, 0, stream>>>(x1, eoc, pk, idx, ppos, out);
}

// Round 9
// 303.971 us; speedup vs baseline: 2.0028x; 1.0604x over previous
//
#include <hip/hip_runtime.h>
#include <hip/hip_bf16.h>
#include <math.h>

#define B 8
#define S 128
#define E 192
#define H 6
#define HD 32
#define L 64
#define NEXP 8
#define ED 768
#define T (B*S)     // 1024
#define SE (S*E)    // 24576
#define LE (L*E)    // 12288

#define SPLITS 64
#define ISPAN 384   // 24576/64
#define CHUNK 128

using s8 = __attribute__((ext_vector_type(8))) short;   // 8 bf16 (4 VGPRs)
using f4 = __attribute__((ext_vector_type(4))) float;   // 4 fp32

// ---------------- RMSNorm1: fp32 out (lat GEMM) + bf16 out (q proj) ----------------
__global__ __launch_bounds__(64) void rmsnorm_bf_k(const float* __restrict__ x,
                                                   const float* __restrict__ w,
                                                   float* __restrict__ y,
                                                   __hip_bfloat16* __restrict__ yb) {
  int row = blockIdx.x;
  int lane = threadIdx.x;
  const float* xr = x + (size_t)row * E;
  float v0 = xr[lane], v1 = xr[lane + 64], v2 = xr[lane + 128];
  float s = v0 * v0 + v1 * v1 + v2 * v2;
#pragma unroll
  for (int off = 32; off > 0; off >>= 1) s += __shfl_xor(s, off);
  float inv = rsqrtf(s * (1.0f / E) + 1e-5f);
  float r0 = v0 * inv * w[lane];
  float r1 = v1 * inv * w[lane + 64];
  float r2 = v2 * inv * w[lane + 128];
  float* yr = y + (size_t)row * E;
  __hip_bfloat16* yrb = yb + (size_t)row * E;
  yr[lane] = r0; yr[lane + 64] = r1; yr[lane + 128] = r2;
  yrb[lane] = __float2bfloat16(r0);
  yrb[lane + 64] = __float2bfloat16(r1);
  yrb[lane + 128] = __float2bfloat16(r2);
}

// ---------------- MEGA: lat_partial (blocks 0..767) + all weight tconv (768..7823) ---
// lat: latent partials over i-splits, grid-equivalent (12 j-blocks, 64 splits).
// tconv: out[n][k] = bf16(in[k][n]) in 32x32 tiles for e1W/swW/e2W/qW/kW/vW/oW.
__global__ __launch_bounds__(256) void mega_k(const float* __restrict__ xn,
                                              const float* __restrict__ latW,
                                              float* __restrict__ part,
                                              const float* __restrict__ e1W,
                                              const float* __restrict__ swW,
                                              const float* __restrict__ e2W,
                                              const float* __restrict__ qW,
                                              const float* __restrict__ kW,
                                              const float* __restrict__ vW,
                                              const float* __restrict__ oW,
                                              __hip_bfloat16* __restrict__ e1Wt,
                                              __hip_bfloat16* __restrict__ swWt,
                                              __hip_bfloat16* __restrict__ e2Wt,
                                              __hip_bfloat16* __restrict__ qWt,
                                              __hip_bfloat16* __restrict__ kWt,
                                              __hip_bfloat16* __restrict__ vWt,
                                              __hip_bfloat16* __restrict__ oWt) {
  __shared__ float smem[1056];   // max(128*8, 32*33)
  const int bid = blockIdx.x;
  const int tid = threadIdx.x;
  if (bid < 768) {
    // ---- latent partial ----
    const int jb = bid % 12, sp = bid / 12;
    const int j = jb * 1024 + tid * 4;
    const int i0 = sp * ISPAN;
    float (*xs)[8] = (float(*)[8])smem;
    f4 acc[8];
#pragma unroll
    for (int b = 0; b < 8; ++b) acc[b] = (f4){0.f, 0.f, 0.f, 0.f};
    for (int c = 0; c < ISPAN; c += CHUNK) {
      __syncthreads();
      for (int l = tid; l < CHUNK * 8; l += 256) {
        int ii = l >> 3, b = l & 7;
        smem[l] = xn[(size_t)b * SE + i0 + c + ii];
      }
      __syncthreads();
#pragma unroll 8
      for (int ii = 0; ii < CHUNK; ++ii) {
        const f4 w = __builtin_nontemporal_load(
            (const f4*)&latW[(size_t)(i0 + c + ii) * LE + j]);
#pragma unroll
        for (int b = 0; b < 8; ++b) {
          float xv = xs[ii][b];
          acc[b][0] += xv * w[0];
          acc[b][1] += xv * w[1];
          acc[b][2] += xv * w[2];
          acc[b][3] += xv * w[3];
        }
      }
    }
#pragma unroll
    for (int b = 0; b < 8; ++b)
      *(f4*)&part[((size_t)sp * 8 + b) * LE + j] = acc[b];
  } else {
    // ---- weight transpose + bf16 ----
    int t = bid - 768;
    const float* in;
    __hip_bfloat16* outp;
    int K, N, kb, nb;
    if (t < 1152) {                       // e1W: [E][ED] per expert
      int e = t / 144, r = t % 144;
      kb = r % 6; nb = r / 6;
      in = e1W + (size_t)e * E * ED; outp = e1Wt + (size_t)e * E * ED;
      K = E; N = ED;
    } else if (t < 1152 + 4608) {         // swW: [ED][ED]
      int t2 = t - 1152;
      int e = t2 / 576, r = t2 % 576;
      kb = r % 24; nb = r / 24;
      in = swW + (size_t)e * ED * ED; outp = swWt + (size_t)e * ED * ED;
      K = ED; N = ED;
    } else if (t < 1152 + 4608 + 1152) {  // e2W: [ED][E]
      int t3 = t - 5760;
      int e = t3 / 144, r = t3 % 144;
      kb = r % 24; nb = r / 24;
      in = e2W + (size_t)e * ED * E; outp = e2Wt + (size_t)e * ED * E;
      K = ED; N = E;
    } else {                              // q/k/v/o: [E][E]
      int t4 = t - 6912;
      int z = t4 / 36, r = t4 % 36;
      kb = r % 6; nb = r / 6;
      in = (z == 0) ? qW : (z == 1) ? kW : (z == 2) ? vW : oW;
      outp = (z == 0) ? qWt : (z == 1) ? kWt : (z == 2) ? vWt : oWt;
      K = E; N = E;
    }
    float (*tile)[33] = (float(*)[33])smem;
    int tx = tid & 31, r8 = tid >> 5;
    int k0 = kb * 32, n0 = nb * 32;
#pragma unroll
    for (int i = 0; i < 4; ++i)
      tile[r8 + 8 * i][tx] = in[(size_t)(k0 + r8 + 8 * i) * N + n0 + tx];
    __syncthreads();
#pragma unroll
    for (int i = 0; i < 4; ++i) {
      int nr = r8 + 8 * i;
      outp[(size_t)(n0 + nr) * K + k0 + tx] = __float2bfloat16(tile[tx][nr]);
    }
  }
}

// reduce partials -> latent, write bf16
__global__ __launch_bounds__(256) void lat_reduce_k(const float* __restrict__ part,
                                                    const float* __restrict__ latb,
                                                    __hip_bfloat16* __restrict__ lat16) {
  int g = blockIdx.x * 256 + threadIdx.x;  // < 8*LE
  int b = g / LE, j = g - b * LE;
  float s = latb[j];
  for (int sp = 0; sp < SPLITS; ++sp) s += part[((size_t)sp * 8 + b) * LE + j];
  lat16[g] = __float2bfloat16(s);
}

// ---------------- q/k/v projections via bf16 MFMA, one dispatch ----------------
__global__ __launch_bounds__(256) void qkv_mm_k(const __hip_bfloat16* __restrict__ xnb,
                                                const __hip_bfloat16* __restrict__ lat16,
                                                const __hip_bfloat16* __restrict__ qWt,
                                                const __hip_bfloat16* __restrict__ kWt,
                                                const __hip_bfloat16* __restrict__ vWt,
                                                const float* __restrict__ qb,
                                                const float* __restrict__ kb,
                                                const float* __restrict__ vb,
                                                float* __restrict__ qo,
                                                float* __restrict__ ko,
                                                float* __restrict__ vo) {
  const int z = blockIdx.z;
  const int M = (z == 0) ? T : (B * L);
  const int m0 = blockIdx.y * 128;
  if (m0 >= M) return;
  const short* A = (const short*)((z == 0) ? xnb : lat16);
  const short* Wt = (const short*)((z == 0) ? qWt : (z == 1) ? kWt : vWt);
  const float* bias = (z == 0) ? qb : (z == 1) ? kb : vb;
  float* C = (z == 0) ? qo : (z == 1) ? ko : vo;
  const int n0 = blockIdx.x * 64;
  __shared__ short As[128 * 64];
  __shared__ short Bs[64 * 64];
  const int tid = threadIdx.x;
  const int lane = tid & 63, wid = tid >> 6;
  const int wr = wid >> 1, wc = wid & 1;
  const int lr = lane & 15, lg = lane >> 4;
  const int slot = tid & 7;
  f4 acc[4][2];
#pragma unroll
  for (int fm = 0; fm < 4; ++fm)
#pragma unroll
    for (int fn = 0; fn < 2; ++fn) acc[fm][fn] = (f4){0.f, 0.f, 0.f, 0.f};
  for (int kb2 = 0; kb2 < E; kb2 += 64) {
    __syncthreads();
#pragma unroll
    for (int p = 0; p < 4; ++p) {
      int row = p * 32 + (tid >> 3);
      s8 v = *(const s8*)(A + (size_t)(m0 + row) * E + kb2 + slot * 8);
      *(s8*)&As[row * 64 + ((slot ^ (row & 7)) << 3)] = v;
    }
#pragma unroll
    for (int p = 0; p < 2; ++p) {
      int row = p * 32 + (tid >> 3);
      s8 v = *(const s8*)(Wt + (size_t)(n0 + row) * E + kb2 + slot * 8);
      *(s8*)&Bs[row * 64 + ((slot ^ (row & 7)) << 3)] = v;
    }
    __syncthreads();
#pragma unroll
    for (int kk = 0; kk < 64; kk += 32) {
      const int sb = (kk >> 3) + lg;
      s8 af[4], bf[2];
#pragma unroll
      for (int fm = 0; fm < 4; ++fm) {
        int row = wr * 64 + fm * 16 + lr;
        af[fm] = *(const s8*)&As[row * 64 + ((sb ^ (row & 7)) << 3)];
      }
#pragma unroll
      for (int fn = 0; fn < 2; ++fn) {
        int row = wc * 32 + fn * 16 + lr;
        bf[fn] = *(const s8*)&Bs[row * 64 + ((sb ^ (row & 7)) << 3)];
      }
#pragma unroll
      for (int fm = 0; fm < 4; ++fm)
#pragma unroll
        for (int fn = 0; fn < 2; ++fn)
          acc[fm][fn] = __builtin_amdgcn_mfma_f32_16x16x32_bf16(af[fm], bf[fn], acc[fm][fn], 0, 0, 0);
    }
  }
#pragma unroll
  for (int fm = 0; fm < 4; ++fm)
#pragma unroll
    for (int fn = 0; fn < 2; ++fn) {
      int col = n0 + wc * 32 + fn * 16 + lr;
      int rowb = m0 + wr * 64 + fm * 16 + lg * 4;
      float bv = bias[col];
#pragma unroll
      for (int j = 0; j < 4; ++j)
        C[(size_t)(rowb + j) * E + col] = acc[fm][fn][j] + bv;
    }
}

// ---------------- o-proj via bf16 MFMA, residual fused ----------------
__global__ __launch_bounds__(256) void oproj_mm_k(const __hip_bfloat16* __restrict__ aob,
                                                  const __hip_bfloat16* __restrict__ oWt,
                                                  const float* __restrict__ ob,
                                                  const float* __restrict__ x,
                                                  float* __restrict__ x1) {
  const int m0 = blockIdx.y * 128;
  const int n0 = blockIdx.x * 64;
  const short* A = (const short*)aob;
  const short* Wt = (const short*)oWt;
  __shared__ short As[128 * 64];
  __shared__ short Bs[64 * 64];
  const int tid = threadIdx.x;
  const int lane = tid & 63, wid = tid >> 6;
  const int wr = wid >> 1, wc = wid & 1;
  const int lr = lane & 15, lg = lane >> 4;
  const int slot = tid & 7;
  f4 acc[4][2];
#pragma unroll
  for (int fm = 0; fm < 4; ++fm)
#pragma unroll
    for (int fn = 0; fn < 2; ++fn) acc[fm][fn] = (f4){0.f, 0.f, 0.f, 0.f};
  for (int kb2 = 0; kb2 < E; kb2 += 64) {
    __syncthreads();
#pragma unroll
    for (int p = 0; p < 4; ++p) {
      int row = p * 32 + (tid >> 3);
      s8 v = *(const s8*)(A + (size_t)(m0 + row) * E + kb2 + slot * 8);
      *(s8*)&As[row * 64 + ((slot ^ (row & 7)) << 3)] = v;
    }
#pragma unroll
    for (int p = 0; p < 2; ++p) {
      int row = p * 32 + (tid >> 3);
      s8 v = *(const s8*)(Wt + (size_t)(n0 + row) * E + kb2 + slot * 8);
      *(s8*)&Bs[row * 64 + ((slot ^ (row & 7)) << 3)] = v;
    }
    __syncthreads();
#pragma unroll
    for (int kk = 0; kk < 64; kk += 32) {
      const int sb = (kk >> 3) + lg;
      s8 af[4], bf[2];
#pragma unroll
      for (int fm = 0; fm < 4; ++fm) {
        int row = wr * 64 + fm * 16 + lr;
        af[fm] = *(const s8*)&As[row * 64 + ((sb ^ (row & 7)) << 3)];
      }
#pragma unroll
      for (int fn = 0; fn < 2; ++fn) {
        int row = wc * 32 + fn * 16 + lr;
        bf[fn] = *(const s8*)&Bs[row * 64 + ((sb ^ (row & 7)) << 3)];
      }
#pragma unroll
      for (int fm = 0; fm < 4; ++fm)
#pragma unroll
        for (int fn = 0; fn < 2; ++fn)
          acc[fm][fn] = __builtin_amdgcn_mfma_f32_16x16x32_bf16(af[fm], bf[fn], acc[fm][fn], 0, 0, 0);
    }
  }
#pragma unroll
  for (int fm = 0; fm < 4; ++fm)
#pragma unroll
    for (int fn = 0; fn < 2; ++fn) {
      int col = n0 + wc * 32 + fn * 16 + lr;
      int rowb = m0 + wr * 64 + fm * 16 + lg * 4;
      float bv = ob[col];
#pragma unroll
      for (int j = 0; j < 4; ++j) {
        size_t off = (size_t)(rowb + j) * E + col;
        x1[off] = acc[fm][fn][j] + bv + x[off];
      }
    }
}

// ---------------- fused rmsnorm2 + router ----------------
__global__ __launch_bounds__(64) void router_rms_k(const float* __restrict__ x1,
                                                   const float* __restrict__ w,
                                                   const float* __restrict__ rW,
                                                   const float* __restrict__ rb,
                                                   __hip_bfloat16* __restrict__ hb,
                                                   float* __restrict__ pk,
                                                   int* __restrict__ idx) {
  int t = blockIdx.x;
  int lane = threadIdx.x;
  const float* xr = x1 + (size_t)t * E;
  float v0 = xr[lane], v1 = xr[lane + 64], v2 = xr[lane + 128];
  float s = v0 * v0 + v1 * v1 + v2 * v2;
#pragma unroll
  for (int off = 32; off > 0; off >>= 1) s += __shfl_xor(s, off);
  float inv = rsqrtf(s * (1.0f / E) + 1e-5f);
  float r0 = v0 * inv * w[lane];
  float r1 = v1 * inv * w[lane + 64];
  float r2 = v2 * inv * w[lane + 128];
  __hip_bfloat16* yrb = hb + (size_t)t * E;
  yrb[lane] = __float2bfloat16(r0);
  yrb[lane + 64] = __float2bfloat16(r1);
  yrb[lane + 128] = __float2bfloat16(r2);
  float lg[8];
#pragma unroll
  for (int n = 0; n < 8; ++n)
    lg[n] = r0 * rW[lane * 8 + n] + r1 * rW[(lane + 64) * 8 + n] + r2 * rW[(lane + 128) * 8 + n];
#pragma unroll
  for (int n = 0; n < 8; ++n)
#pragma unroll
    for (int off = 32; off > 0; off >>= 1) lg[n] += __shfl_xor(lg[n], off);
  if (lane == 0) {
#pragma unroll
    for (int n = 0; n < 8; ++n) lg[n] += rb[n];
    float mx = lg[0];
#pragma unroll
    for (int n = 1; n < 8; ++n) mx = fmaxf(mx, lg[n]);
    float p[8], sum = 0.f;
#pragma unroll
    for (int n = 0; n < 8; ++n) { p[n] = __expf(lg[n] - mx); sum += p[n]; }
    float isum = 1.f / sum;
#pragma unroll
    for (int n = 0; n < 8; ++n) p[n] *= isum;
    int i0 = 0;
#pragma unroll
    for (int n = 1; n < 8; ++n) if (p[n] > p[i0]) i0 = n;
    int i1 = (i0 == 0) ? 1 : 0;
#pragma unroll
    for (int n = 0; n < 8; ++n) if (n != i0 && p[n] > p[i1]) i1 = n;
    pk[t * 2] = p[i0];
    pk[t * 2 + 1] = p[i1];
    idx[t * 2] = i0;
    idx[t * 2 + 1] = i1;
  }
}

// ---------------- deterministic per-expert compaction ----------------
__global__ __launch_bounds__(512) void compact_k(const int* __restrict__ idx,
                                                 int* __restrict__ toklist,
                                                 int* __restrict__ ppos,
                                                 int* __restrict__ cnt) {
  int e = threadIdx.x >> 6;
  int lane = threadIdx.x & 63;
  int pos = 0;
  for (int base = 0; base < T; base += 64) {
    int t = base + lane;
    int i0 = idx[t * 2], i1 = idx[t * 2 + 1];
    bool sel = (i0 == e) || (i1 == e);
    unsigned long long m = __ballot(sel);
    int myoff = __popcll(m & ((1ull << lane) - 1ull));
    if (sel) {
      int p = pos + myoff;
      toklist[e * T + p] = t;
      ppos[t * 2 + ((i0 == e) ? 0 : 1)] = p;
    }
    pos += __popcll(m);
  }
  if (lane == 0) cnt[e] = pos;
}

// ---------------- bf16 MFMA GEMM over compact rows ----------------
// flags: 1 = relu, 2 = fp32 output, 4 = gather A rows via toklist.
__global__ __launch_bounds__(256) void moe_gemm_g(const __hip_bfloat16* __restrict__ A_,
                                                  const __hip_bfloat16* __restrict__ Wt_,
                                                  const float* __restrict__ bias_,
                                                  void* __restrict__ C_,
                                                  const int* __restrict__ toklist,
                                                  const int* __restrict__ cntp,
                                                  int N, int K,
                                                  long aB, long wB, long bB, long cB,
                                                  int flags) {
  const int e = blockIdx.z;
  const int cnt = cntp[e];
  const int m0 = blockIdx.y * 128;
  if (m0 >= cnt) return;
  const short* A = (const short*)A_ + ((flags & 4) ? 0 : (size_t)e * aB);
  const short* Wt = (const short*)Wt_ + (size_t)e * wB;
  const float* bias = bias_ + (size_t)e * bB;
  const int n0 = blockIdx.x * 64;
  __shared__ short As[128 * 64];
  __shared__ short Bs[64 * 64];
  const int tid = threadIdx.x;
  const int lane = tid & 63, wid = tid >> 6;
  const int wr = wid >> 1, wc = wid & 1;
  const int lr = lane & 15, lg = lane >> 4;
  long arow_off[4];
#pragma unroll
  for (int p = 0; p < 4; ++p) {
    int row = p * 32 + (tid >> 3);
    int gr = m0 + row;
    int src;
    if (flags & 4) src = (gr < cnt) ? toklist[e * T + gr] : toklist[e * T];
    else src = gr;
    arow_off[p] = (size_t)src * K;
  }
  f4 acc[4][2];
#pragma unroll
  for (int fm = 0; fm < 4; ++fm)
#pragma unroll
    for (int fn = 0; fn < 2; ++fn) acc[fm][fn] = (f4){0.f, 0.f, 0.f, 0.f};
  const int slot = tid & 7;
  for (int kb = 0; kb < K; kb += 64) {
    __syncthreads();
#pragma unroll
    for (int p = 0; p < 4; ++p) {
      int row = p * 32 + (tid >> 3);
      s8 v = *(const s8*)(A + arow_off[p] + kb + slot * 8);
      *(s8*)&As[row * 64 + ((slot ^ (row & 7)) << 3)] = v;
    }
#pragma unroll
    for (int p = 0; p < 2; ++p) {
      int row = p * 32 + (tid >> 3);
      s8 v = *(const s8*)(Wt + (size_t)(n0 + row) * K + kb + slot * 8);
      *(s8*)&Bs[row * 64 + ((slot ^ (row & 7)) << 3)] = v;
    }
    __syncthreads();
#pragma unroll
    for (int kk = 0; kk < 64; kk += 32) {
      const int sb = (kk >> 3) + lg;
      s8 af[4], bf[2];
#pragma unroll
      for (int fm = 0; fm < 4; ++fm) {
        int row = wr * 64 + fm * 16 + lr;
        af[fm] = *(const s8*)&As[row * 64 + ((sb ^ (row & 7)) << 3)];
      }
#pragma unroll
      for (int fn = 0; fn < 2; ++fn) {
        int row = wc * 32 + fn * 16 + lr;
        bf[fn] = *(const s8*)&Bs[row * 64 + ((sb ^ (row & 7)) << 3)];
      }
#pragma unroll
      for (int fm = 0; fm < 4; ++fm)
#pragma unroll
        for (int fn = 0; fn < 2; ++fn)
          acc[fm][fn] = __builtin_amdgcn_mfma_f32_16x16x32_bf16(af[fm], bf[fn], acc[fm][fn], 0, 0, 0);
    }
  }
#pragma unroll
  for (int fm = 0; fm < 4; ++fm) {
#pragma unroll
    for (int fn = 0; fn < 2; ++fn) {
      int col = n0 + wc * 32 + fn * 16 + lr;
      int rowb = m0 + wr * 64 + fm * 16 + lg * 4;
      float bv = bias[col];
#pragma unroll
      for (int j = 0; j < 4; ++j) {
        if (rowb + j >= cnt) continue;
        float v = acc[fm][fn][j] + bv;
        if (flags & 1) v = fmaxf(v, 0.f);
        if (flags & 2)
          ((float*)C_)[(size_t)e * cB + (size_t)(rowb + j) * N + col] = v;
        else
          ((__hip_bfloat16*)C_)[(size_t)e * cB + (size_t)(rowb + j) * N + col] = __float2bfloat16(v);
      }
    }
  }
}

// ---------------- attention v2: 256 thr, 2 lanes/query, score LDS, RoPE table -------
__global__ __launch_bounds__(256) void attn_k(const float* __restrict__ q,
                                              const float* __restrict__ kk,
                                              const float* __restrict__ vv,
                                              __hip_bfloat16* __restrict__ aob) {
  int b = blockIdx.x / H, h = blockIdx.x % H;
  __shared__ float ks[64][32], vs[64][32];
  __shared__ float sc[64][128];
  const int tid = threadIdx.x;
#pragma unroll
  for (int i = 0; i < 2; ++i) {
    int fi = tid + 256 * i;          // [0,512)
    int l = fi >> 3, c = (fi & 7) << 2;
    *(float4*)&ks[l][c] = *(const float4*)&kk[(size_t)(b * L + l) * E + h * HD + c];
    *(float4*)&vs[l][c] = *(const float4*)&vv[(size_t)(b * L + l) * E + h * HD + c];
  }
  __syncthreads();
  const int qrow = tid >> 1, half = tid & 1;
  const float* qp = &q[(size_t)(b * S + qrow) * E + h * HD + half * 16];
  float qv[16];
#pragma unroll
  for (int d = 0; d < 16; ++d) qv[d] = qp[d];
  // RoPE: pair (2dd,2dd+1) within this half; global pair index = half*8+dd
  const float TBL[16] = {
    1.0f, 0.5623413251903491f, 0.31622776601683794f, 0.17782794100389228f,
    0.1f, 0.05623413251903491f, 0.031622776601683794f, 0.017782794100389228f,
    0.01f, 0.005623413251903491f, 0.0031622776601683794f, 0.0017782794100389228f,
    0.001f, 0.0005623413251903491f, 0.00031622776601683794f, 0.00017782794100389228f};
#pragma unroll
  for (int dd = 0; dd < 8; ++dd) {
    float ang = (float)qrow * TBL[half * 8 + dd];
    float sn, cs;
    __sincosf(ang, &sn, &cs);
    float x1 = qv[2 * dd], x2 = qv[2 * dd + 1];
    qv[2 * dd] = x1 * cs - x2 * sn;
    qv[2 * dd + 1] = x1 * sn + x2 * cs;
  }
  const float scale = 0.17677669529663687f;  // 1/sqrt(32)
#pragma unroll
  for (int d = 0; d < 16; ++d) qv[d] *= scale;
  const int cbase = half * 16;
  float mx = -1e30f;
  for (int l = 0; l < 64; ++l) {
    float p = 0.f;
#pragma unroll
    for (int d = 0; d < 16; ++d) p += qv[d] * ks[l][cbase + d];
    p += __shfl_xor(p, 1);
    if (!half) sc[l][qrow] = p;
    mx = fmaxf(mx, p);
  }
  __syncthreads();
  float o[16];
#pragma unroll
  for (int d = 0; d < 16; ++d) o[d] = 0.f;
  float sum = 0.f;
  for (int l = 0; l < 64; ++l) {
    float wgt = __expf(sc[l][qrow] - mx);
    sum += wgt;
#pragma unroll
    for (int d = 0; d < 16; ++d) o[d] += wgt * vs[l][cbase + d];
  }
  float inv = 1.0f / sum;
  __hip_bfloat16* op = &aob[(size_t)(b * S + qrow) * E + h * HD + cbase];
#pragma unroll
  for (int d = 0; d < 16; ++d) op[d] = __float2bfloat16(o[d] * inv);
}

// ---------------- combine ----------------
__global__ __launch_bounds__(256) void combine_k(const float* __restrict__ x1,
                                                 const float* __restrict__ eoc,
                                                 const float* __restrict__ pk,
                                                 const int* __restrict__ idx,
                                                 const int* __restrict__ ppos,
                                                 float* __restrict__ out) {
  int g = blockIdx.x * 256 + threadIdx.x;  // T*E = 196608
  int t = g / E;
  int e = g - t * E;
  int i0 = idx[t * 2], i1 = idx[t * 2 + 1];
  int p0 = ppos[t * 2], p1 = ppos[t * 2 + 1];
  out[g] = x1[g] + pk[t * 2] * eoc[((size_t)i0 * T + p0) * E + e]
                 + pk[t * 2 + 1] * eoc[((size_t)i1 * T + p1) * E + e];
}

extern "C" void kernel_launch(void* const* d_in, const int* in_sizes, int n_in,
                              void* d_out, int out_size, void* d_ws, size_t ws_size,
                              hipStream_t stream) {
  const float* x    = (const float*)d_in[0];
  const float* r1w  = (const float*)d_in[1];
  const float* r2w  = (const float*)d_in[2];
  const float* latW = (const float*)d_in[3];
  const float* latb = (const float*)d_in[4];
  const float* qW   = (const float*)d_in[5];
  const float* qb   = (const float*)d_in[6];
  const float* kW   = (const float*)d_in[7];
  const float* kb   = (const float*)d_in[8];
  const float* vW   = (const float*)d_in[9];
  const float* vb   = (const float*)d_in[10];
  const float* oW   = (const float*)d_in[11];
  const float* ob   = (const float*)d_in[12];
  const float* rW   = (const float*)d_in[13];
  const float* rb   = (const float*)d_in[14];
  const float* e1W  = (const float*)d_in[15];
  const float* e1b  = (const float*)d_in[16];
  const float* swW  = (const float*)d_in[17];
  const float* swb  = (const float*)d_in[18];
  const float* e2W  = (const float*)d_in[19];
  const float* e2b  = (const float*)d_in[20];
  float* out = (float*)d_out;

  float* ws = (float*)d_ws;
  float* xn1  = ws;                                         // 196608 f32
  __hip_bfloat16* xnb   = (__hip_bfloat16*)(ws + 196608);   // 196608 bf16
  __hip_bfloat16* lat16 = (__hip_bfloat16*)(ws + 294912);   // 98304 bf16
  float* qbuf = ws + 344064;            // 196608 f32
  float* kbuf = ws + 540672;            // 98304
  float* vbuf = ws + 638976;            // 98304
  __hip_bfloat16* aob   = (__hip_bfloat16*)(ws + 737280);   // 196608 bf16
  float* x1   = ws + 835584;            // 196608
  float* pk   = ws + 1032192;           // 2048
  int*   idx  = (int*)(ws + 1034240);   // 2048
  int*   toklist = (int*)(ws + 1036288);  // 8192
  int*   ppos    = (int*)(ws + 1044480);  // 2048
  int*   cnt     = (int*)(ws + 1046528);  // 8 (pad 256)
  __hip_bfloat16* qWt = (__hip_bfloat16*)(ws + 1046784);    // 36864 bf16
  __hip_bfloat16* kWt = (__hip_bfloat16*)(ws + 1065216);
  __hip_bfloat16* vWt = (__hip_bfloat16*)(ws + 1083648);
  __hip_bfloat16* oWt = (__hip_bfloat16*)(ws + 1102080);
  __hip_bfloat16* hb    = (__hip_bfloat16*)(ws + 1120512);  // 196608 bf16
  __hip_bfloat16* e1Wt  = (__hip_bfloat16*)(ws + 1218816);  // 1179648 bf16
  __hip_bfloat16* swWt  = (__hip_bfloat16*)(ws + 1808640);  // 4718592 bf16
  __hip_bfloat16* e2Wt  = (__hip_bfloat16*)(ws + 4167936);  // 1179648 bf16
  __hip_bfloat16* t1    = (__hip_bfloat16*)(ws + 4757760);  // 6291456 bf16
  __hip_bfloat16* t2    = (__hip_bfloat16*)(ws + 7903488);  // 6291456 bf16
  float* eoc  = ws + 11049216;          // 1572864 f32
  float* part = ws + 12622080;          // 6291456 f32

  // 1) rmsnorm1 (fp32 + bf16)
  rmsnorm_bf_k<<<T, 64, 0, stream>>>(x, r1w, xn1, xnb);
  // 2) MEGA: latent partials (768 blocks) + all weight tconv backfill (7056 blocks)
  mega_k<<<7824, 256, 0, stream>>>(xn1, latW, part,
                                   e1W, swW, e2W, qW, kW, vW, oW,
                                   e1Wt, swWt, e2Wt, qWt, kWt, vWt, oWt);
  // 3) reduce partials -> lat16
  lat_reduce_k<<<(8 * LE) / 256, 256, 0, stream>>>(part, latb, lat16);
  // 4) q,k,v projections via MFMA
  qkv_mm_k<<<dim3(3, 8, 3), 256, 0, stream>>>(xnb, lat16, qWt, kWt, vWt,
                                              qb, kb, vb, qbuf, kbuf, vbuf);
  // 5) attention v2 (rope fused) -> bf16
  attn_k<<<B * H, 256, 0, stream>>>(qbuf, kbuf, vbuf, aob);
  // 6) o-proj + residual via MFMA
  oproj_mm_k<<<dim3(3, 8), 256, 0, stream>>>(aob, oWt, ob, x, x1);
  // 7) rmsnorm2 + router fused
  router_rms_k<<<T, 64, 0, stream>>>(x1, r2w, rW, rb, hb, pk, idx);
  // 8) deterministic compaction
  compact_k<<<1, 512, 0, stream>>>(idx, toklist, ppos, cnt);
  // 9) MoE top-2 stages (compact rows, early exit)
  moe_gemm_g<<<dim3(ED / 64, 8, NEXP), 256, 0, stream>>>(
      hb, e1Wt, e1b, t1, toklist, cnt, ED, E, 0, (long)ED * E, ED, (long)T * ED, 4);
  moe_gemm_g<<<dim3(ED / 64, 8, NEXP), 256, 0, stream>>>(
      t1, swWt, swb, t2, toklist, cnt, ED, ED, (long)T * ED, (long)ED * ED, ED, (long)T * ED, 1);
  moe_gemm_g<<<dim3(E / 64, 8, NEXP), 256, 0, stream>>>(
      t2, e2Wt, e2b, eoc, toklist, cnt, E, ED, (long)T * ED, (long)E * ED, E, (long)T * E, 2);
  // 10) combine
  combine_k<<<(T * E) / 256, 256, 0, stream>>>(x1, eoc, pk, idx, ppos, out);
}

// Round 11
// 302.913 us; speedup vs baseline: 2.0098x; 1.0035x over previous
//
#include <hip/hip_runtime.h>
#include <hip/hip_bf16.h>
#include <math.h>

#define B 8
#define S 128
#define E 192
#define H 6
#define HD 32
#define L 64
#define NEXP 8
#define ED 768
#define T (B*S)     // 1024
#define SE (S*E)    // 24576
#define LE (L*E)    // 12288

#define SPLITS 64
#define ISPAN 384   // 24576/64
#define CHUNK 128

using s8 = __attribute__((ext_vector_type(8))) short;   // 8 bf16 (4 VGPRs)
using f4 = __attribute__((ext_vector_type(4))) float;   // 4 fp32

// ---------------- RMSNorm1: fp32 out (lat GEMM) + bf16 out (q proj) ----------------
__global__ __launch_bounds__(64) void rmsnorm_bf_k(const float* __restrict__ x,
                                                   const float* __restrict__ w,
                                                   float* __restrict__ y,
                                                   __hip_bfloat16* __restrict__ yb) {
  int row = blockIdx.x;
  int lane = threadIdx.x;
  const float* xr = x + (size_t)row * E;
  float v0 = xr[lane], v1 = xr[lane + 64], v2 = xr[lane + 128];
  float s = v0 * v0 + v1 * v1 + v2 * v2;
#pragma unroll
  for (int off = 32; off > 0; off >>= 1) s += __shfl_xor(s, off);
  float inv = rsqrtf(s * (1.0f / E) + 1e-5f);
  float r0 = v0 * inv * w[lane];
  float r1 = v1 * inv * w[lane + 64];
  float r2 = v2 * inv * w[lane + 128];
  float* yr = y + (size_t)row * E;
  __hip_bfloat16* yrb = yb + (size_t)row * E;
  yr[lane] = r0; yr[lane + 64] = r1; yr[lane + 128] = r2;
  yrb[lane] = __float2bfloat16(r0);
  yrb[lane + 64] = __float2bfloat16(r1);
  yrb[lane + 128] = __float2bfloat16(r2);
}

// ---------------- MEGA: lat_partial (blocks 0..767) + all weight tconv (768..7823) ---
__global__ __launch_bounds__(256) void mega_k(const float* __restrict__ xn,
                                              const float* __restrict__ latW,
                                              float* __restrict__ part,
                                              const float* __restrict__ e1W,
                                              const float* __restrict__ swW,
                                              const float* __restrict__ e2W,
                                              const float* __restrict__ qW,
                                              const float* __restrict__ kW,
                                              const float* __restrict__ vW,
                                              const float* __restrict__ oW,
                                              __hip_bfloat16* __restrict__ e1Wt,
                                              __hip_bfloat16* __restrict__ swWt,
                                              __hip_bfloat16* __restrict__ e2Wt,
                                              __hip_bfloat16* __restrict__ qWt,
                                              __hip_bfloat16* __restrict__ kWt,
                                              __hip_bfloat16* __restrict__ vWt,
                                              __hip_bfloat16* __restrict__ oWt) {
  __shared__ float smem[1056];   // max(128*8, 32*33)
  const int bid = blockIdx.x;
  const int tid = threadIdx.x;
  if (bid < 768) {
    const int jb = bid % 12, sp = bid / 12;
    const int j = jb * 1024 + tid * 4;
    const int i0 = sp * ISPAN;
    float (*xs)[8] = (float(*)[8])smem;
    f4 acc[8];
#pragma unroll
    for (int b = 0; b < 8; ++b) acc[b] = (f4){0.f, 0.f, 0.f, 0.f};
    for (int c = 0; c < ISPAN; c += CHUNK) {
      __syncthreads();
      for (int l = tid; l < CHUNK * 8; l += 256) {
        int ii = l >> 3, b = l & 7;
        smem[l] = xn[(size_t)b * SE + i0 + c + ii];
      }
      __syncthreads();
#pragma unroll 8
      for (int ii = 0; ii < CHUNK; ++ii) {
        const f4 w = __builtin_nontemporal_load(
            (const f4*)&latW[(size_t)(i0 + c + ii) * LE + j]);
#pragma unroll
        for (int b = 0; b < 8; ++b) {
          float xv = xs[ii][b];
          acc[b][0] += xv * w[0];
          acc[b][1] += xv * w[1];
          acc[b][2] += xv * w[2];
          acc[b][3] += xv * w[3];
        }
      }
    }
#pragma unroll
    for (int b = 0; b < 8; ++b)
      *(f4*)&part[((size_t)sp * 8 + b) * LE + j] = acc[b];
  } else {
    int t = bid - 768;
    const float* in;
    __hip_bfloat16* outp;
    int K, N, kb, nb;
    if (t < 1152) {                       // e1W: [E][ED] per expert
      int e = t / 144, r = t % 144;
      kb = r % 6; nb = r / 6;
      in = e1W + (size_t)e * E * ED; outp = e1Wt + (size_t)e * E * ED;
      K = E; N = ED;
    } else if (t < 1152 + 4608) {         // swW: [ED][ED]
      int t2 = t - 1152;
      int e = t2 / 576, r = t2 % 576;
      kb = r % 24; nb = r / 24;
      in = swW + (size_t)e * ED * ED; outp = swWt + (size_t)e * ED * ED;
      K = ED; N = ED;
    } else if (t < 1152 + 4608 + 1152) {  // e2W: [ED][E]
      int t3 = t - 5760;
      int e = t3 / 144, r = t3 % 144;
      kb = r % 24; nb = r / 24;
      in = e2W + (size_t)e * ED * E; outp = e2Wt + (size_t)e * ED * E;
      K = ED; N = E;
    } else {                              // q/k/v/o: [E][E]
      int t4 = t - 6912;
      int z = t4 / 36, r = t4 % 36;
      kb = r % 6; nb = r / 6;
      in = (z == 0) ? qW : (z == 1) ? kW : (z == 2) ? vW : oW;
      outp = (z == 0) ? qWt : (z == 1) ? kWt : (z == 2) ? vWt : oWt;
      K = E; N = E;
    }
    float (*tile)[33] = (float(*)[33])smem;
    int tx = tid & 31, r8 = tid >> 5;
    int k0 = kb * 32, n0 = nb * 32;
#pragma unroll
    for (int i = 0; i < 4; ++i)
      tile[r8 + 8 * i][tx] = in[(size_t)(k0 + r8 + 8 * i) * N + n0 + tx];
    __syncthreads();
#pragma unroll
    for (int i = 0; i < 4; ++i) {
      int nr = r8 + 8 * i;
      outp[(size_t)(n0 + nr) * K + k0 + tx] = __float2bfloat16(tile[tx][nr]);
    }
  }
}

// reduce partials -> latent, write bf16
__global__ __launch_bounds__(256) void lat_reduce_k(const float* __restrict__ part,
                                                    const float* __restrict__ latb,
                                                    __hip_bfloat16* __restrict__ lat16) {
  int g = blockIdx.x * 256 + threadIdx.x;  // < 8*LE
  int b = g / LE, j = g - b * LE;
  float s = latb[j];
  for (int sp = 0; sp < SPLITS; ++sp) s += part[((size_t)sp * 8 + b) * LE + j];
  lat16[g] = __float2bfloat16(s);
}

// ---------------- q/k/v projections via bf16 MFMA, one dispatch ----------------
__global__ __launch_bounds__(256) void qkv_mm_k(const __hip_bfloat16* __restrict__ xnb,
                                                const __hip_bfloat16* __restrict__ lat16,
                                                const __hip_bfloat16* __restrict__ qWt,
                                                const __hip_bfloat16* __restrict__ kWt,
                                                const __hip_bfloat16* __restrict__ vWt,
                                                const float* __restrict__ qb,
                                                const float* __restrict__ kb,
                                                const float* __restrict__ vb,
                                                float* __restrict__ qo,
                                                float* __restrict__ ko,
                                                float* __restrict__ vo) {
  const int z = blockIdx.z;
  const int M = (z == 0) ? T : (B * L);
  const int m0 = blockIdx.y * 128;
  if (m0 >= M) return;
  const short* A = (const short*)((z == 0) ? xnb : lat16);
  const short* Wt = (const short*)((z == 0) ? qWt : (z == 1) ? kWt : vWt);
  const float* bias = (z == 0) ? qb : (z == 1) ? kb : vb;
  float* C = (z == 0) ? qo : (z == 1) ? ko : vo;
  const int n0 = blockIdx.x * 64;
  __shared__ short As[128 * 64];
  __shared__ short Bs[64 * 64];
  const int tid = threadIdx.x;
  const int lane = tid & 63, wid = tid >> 6;
  const int wr = wid >> 1, wc = wid & 1;
  const int lr = lane & 15, lg = lane >> 4;
  const int slot = tid & 7;
  f4 acc[4][2];
#pragma unroll
  for (int fm = 0; fm < 4; ++fm)
#pragma unroll
    for (int fn = 0; fn < 2; ++fn) acc[fm][fn] = (f4){0.f, 0.f, 0.f, 0.f};
  for (int kb2 = 0; kb2 < E; kb2 += 64) {
    __syncthreads();
#pragma unroll
    for (int p = 0; p < 4; ++p) {
      int row = p * 32 + (tid >> 3);
      s8 v = *(const s8*)(A + (size_t)(m0 + row) * E + kb2 + slot * 8);
      *(s8*)&As[row * 64 + ((slot ^ (row & 7)) << 3)] = v;
    }
#pragma unroll
    for (int p = 0; p < 2; ++p) {
      int row = p * 32 + (tid >> 3);
      s8 v = *(const s8*)(Wt + (size_t)(n0 + row) * E + kb2 + slot * 8);
      *(s8*)&Bs[row * 64 + ((slot ^ (row & 7)) << 3)] = v;
    }
    __syncthreads();
#pragma unroll
    for (int kk = 0; kk < 64; kk += 32) {
      const int sb = (kk >> 3) + lg;
      s8 af[4], bf[2];
#pragma unroll
      for (int fm = 0; fm < 4; ++fm) {
        int row = wr * 64 + fm * 16 + lr;
        af[fm] = *(const s8*)&As[row * 64 + ((sb ^ (row & 7)) << 3)];
      }
#pragma unroll
      for (int fn = 0; fn < 2; ++fn) {
        int row = wc * 32 + fn * 16 + lr;
        bf[fn] = *(const s8*)&Bs[row * 64 + ((sb ^ (row & 7)) << 3)];
      }
#pragma unroll
      for (int fm = 0; fm < 4; ++fm)
#pragma unroll
        for (int fn = 0; fn < 2; ++fn)
          acc[fm][fn] = __builtin_amdgcn_mfma_f32_16x16x32_bf16(af[fm], bf[fn], acc[fm][fn], 0, 0, 0);
    }
  }
#pragma unroll
  for (int fm = 0; fm < 4; ++fm)
#pragma unroll
    for (int fn = 0; fn < 2; ++fn) {
      int col = n0 + wc * 32 + fn * 16 + lr;
      int rowb = m0 + wr * 64 + fm * 16 + lg * 4;
      float bv = bias[col];
#pragma unroll
      for (int j = 0; j < 4; ++j)
        C[(size_t)(rowb + j) * E + col] = acc[fm][fn][j] + bv;
    }
}

// ---------------- o-proj via bf16 MFMA, residual fused ----------------
__global__ __launch_bounds__(256) void oproj_mm_k(const __hip_bfloat16* __restrict__ aob,
                                                  const __hip_bfloat16* __restrict__ oWt,
                                                  const float* __restrict__ ob,
                                                  const float* __restrict__ x,
                                                  float* __restrict__ x1) {
  const int m0 = blockIdx.y * 128;
  const int n0 = blockIdx.x * 64;
  const short* A = (const short*)aob;
  const short* Wt = (const short*)oWt;
  __shared__ short As[128 * 64];
  __shared__ short Bs[64 * 64];
  const int tid = threadIdx.x;
  const int lane = tid & 63, wid = tid >> 6;
  const int wr = wid >> 1, wc = wid & 1;
  const int lr = lane & 15, lg = lane >> 4;
  const int slot = tid & 7;
  f4 acc[4][2];
#pragma unroll
  for (int fm = 0; fm < 4; ++fm)
#pragma unroll
    for (int fn = 0; fn < 2; ++fn) acc[fm][fn] = (f4){0.f, 0.f, 0.f, 0.f};
  for (int kb2 = 0; kb2 < E; kb2 += 64) {
    __syncthreads();
#pragma unroll
    for (int p = 0; p < 4; ++p) {
      int row = p * 32 + (tid >> 3);
      s8 v = *(const s8*)(A + (size_t)(m0 + row) * E + kb2 + slot * 8);
      *(s8*)&As[row * 64 + ((slot ^ (row & 7)) << 3)] = v;
    }
#pragma unroll
    for (int p = 0; p < 2; ++p) {
      int row = p * 32 + (tid >> 3);
      s8 v = *(const s8*)(Wt + (size_t)(n0 + row) * E + kb2 + slot * 8);
      *(s8*)&Bs[row * 64 + ((slot ^ (row & 7)) << 3)] = v;
    }
    __syncthreads();
#pragma unroll
    for (int kk = 0; kk < 64; kk += 32) {
      const int sb = (kk >> 3) + lg;
      s8 af[4], bf[2];
#pragma unroll
      for (int fm = 0; fm < 4; ++fm) {
        int row = wr * 64 + fm * 16 + lr;
        af[fm] = *(const s8*)&As[row * 64 + ((sb ^ (row & 7)) << 3)];
      }
#pragma unroll
      for (int fn = 0; fn < 2; ++fn) {
        int row = wc * 32 + fn * 16 + lr;
        bf[fn] = *(const s8*)&Bs[row * 64 + ((sb ^ (row & 7)) << 3)];
      }
#pragma unroll
      for (int fm = 0; fm < 4; ++fm)
#pragma unroll
        for (int fn = 0; fn < 2; ++fn)
          acc[fm][fn] = __builtin_amdgcn_mfma_f32_16x16x32_bf16(af[fm], bf[fn], acc[fm][fn], 0, 0, 0);
    }
  }
#pragma unroll
  for (int fm = 0; fm < 4; ++fm)
#pragma unroll
    for (int fn = 0; fn < 2; ++fn) {
      int col = n0 + wc * 32 + fn * 16 + lr;
      int rowb = m0 + wr * 64 + fm * 16 + lg * 4;
      float bv = ob[col];
#pragma unroll
      for (int j = 0; j < 4; ++j) {
        size_t off = (size_t)(rowb + j) * E + col;
        x1[off] = acc[fm][fn][j] + bv + x[off];
      }
    }
}

// ---------------- fused rmsnorm2 + router ----------------
__global__ __launch_bounds__(64) void router_rms_k(const float* __restrict__ x1,
                                                   const float* __restrict__ w,
                                                   const float* __restrict__ rW,
                                                   const float* __restrict__ rb,
                                                   __hip_bfloat16* __restrict__ hb,
                                                   float* __restrict__ pk,
                                                   int* __restrict__ idx) {
  int t = blockIdx.x;
  int lane = threadIdx.x;
  const float* xr = x1 + (size_t)t * E;
  float v0 = xr[lane], v1 = xr[lane + 64], v2 = xr[lane + 128];
  float s = v0 * v0 + v1 * v1 + v2 * v2;
#pragma unroll
  for (int off = 32; off > 0; off >>= 1) s += __shfl_xor(s, off);
  float inv = rsqrtf(s * (1.0f / E) + 1e-5f);
  float r0 = v0 * inv * w[lane];
  float r1 = v1 * inv * w[lane + 64];
  float r2 = v2 * inv * w[lane + 128];
  __hip_bfloat16* yrb = hb + (size_t)t * E;
  yrb[lane] = __float2bfloat16(r0);
  yrb[lane + 64] = __float2bfloat16(r1);
  yrb[lane + 128] = __float2bfloat16(r2);
  float lg[8];
#pragma unroll
  for (int n = 0; n < 8; ++n)
    lg[n] = r0 * rW[lane * 8 + n] + r1 * rW[(lane + 64) * 8 + n] + r2 * rW[(lane + 128) * 8 + n];
#pragma unroll
  for (int n = 0; n < 8; ++n)
#pragma unroll
    for (int off = 32; off > 0; off >>= 1) lg[n] += __shfl_xor(lg[n], off);
  if (lane == 0) {
#pragma unroll
    for (int n = 0; n < 8; ++n) lg[n] += rb[n];
    float mx = lg[0];
#pragma unroll
    for (int n = 1; n < 8; ++n) mx = fmaxf(mx, lg[n]);
    float p[8], sum = 0.f;
#pragma unroll
    for (int n = 0; n < 8; ++n) { p[n] = __expf(lg[n] - mx); sum += p[n]; }
    float isum = 1.f / sum;
#pragma unroll
    for (int n = 0; n < 8; ++n) p[n] *= isum;
    int i0 = 0;
#pragma unroll
    for (int n = 1; n < 8; ++n) if (p[n] > p[i0]) i0 = n;
    int i1 = (i0 == 0) ? 1 : 0;
#pragma unroll
    for (int n = 0; n < 8; ++n) if (n != i0 && p[n] > p[i1]) i1 = n;
    pk[t * 2] = p[i0];
    pk[t * 2 + 1] = p[i1];
    idx[t * 2] = i0;
    idx[t * 2 + 1] = i1;
  }
}

// ---------------- deterministic per-expert compaction ----------------
__global__ __launch_bounds__(512) void compact_k(const int* __restrict__ idx,
                                                 int* __restrict__ toklist,
                                                 int* __restrict__ ppos,
                                                 int* __restrict__ cnt) {
  int e = threadIdx.x >> 6;
  int lane = threadIdx.x & 63;
  int pos = 0;
  for (int base = 0; base < T; base += 64) {
    int t = base + lane;
    int i0 = idx[t * 2], i1 = idx[t * 2 + 1];
    bool sel = (i0 == e) || (i1 == e);
    unsigned long long m = __ballot(sel);
    int myoff = __popcll(m & ((1ull << lane) - 1ull));
    if (sel) {
      int p = pos + myoff;
      toklist[e * T + p] = t;
      ppos[t * 2 + ((i0 == e) ? 0 : 1)] = p;
    }
    pos += __popcll(m);
  }
  if (lane == 0) cnt[e] = pos;
}

// ---------------- bf16 MFMA GEMM over compact rows ----------------
// flags: 1 = relu, 2 = fp32 output, 4 = gather A rows via toklist.
__global__ __launch_bounds__(256) void moe_gemm_g(const __hip_bfloat16* __restrict__ A_,
                                                  const __hip_bfloat16* __restrict__ Wt_,
                                                  const float* __restrict__ bias_,
                                                  void* __restrict__ C_,
                                                  const int* __restrict__ toklist,
                                                  const int* __restrict__ cntp,
                                                  int N, int K,
                                                  long aB, long wB, long bB, long cB,
                                                  int flags) {
  const int e = blockIdx.z;
  const int cnt = cntp[e];
  const int m0 = blockIdx.y * 128;
  if (m0 >= cnt) return;
  const short* A = (const short*)A_ + ((flags & 4) ? 0 : (size_t)e * aB);
  const short* Wt = (const short*)Wt_ + (size_t)e * wB;
  const float* bias = bias_ + (size_t)e * bB;
  const int n0 = blockIdx.x * 64;
  __shared__ short As[128 * 64];
  __shared__ short Bs[64 * 64];
  const int tid = threadIdx.x;
  const int lane = tid & 63, wid = tid >> 6;
  const int wr = wid >> 1, wc = wid & 1;
  const int lr = lane & 15, lg = lane >> 4;
  long arow_off[4];
#pragma unroll
  for (int p = 0; p < 4; ++p) {
    int row = p * 32 + (tid >> 3);
    int gr = m0 + row;
    int src;
    if (flags & 4) src = (gr < cnt) ? toklist[e * T + gr] : toklist[e * T];
    else src = gr;
    arow_off[p] = (size_t)src * K;
  }
  f4 acc[4][2];
#pragma unroll
  for (int fm = 0; fm < 4; ++fm)
#pragma unroll
    for (int fn = 0; fn < 2; ++fn) acc[fm][fn] = (f4){0.f, 0.f, 0.f, 0.f};
  const int slot = tid & 7;
  for (int kb = 0; kb < K; kb += 64) {
    __syncthreads();
#pragma unroll
    for (int p = 0; p < 4; ++p) {
      int row = p * 32 + (tid >> 3);
      s8 v = *(const s8*)(A + arow_off[p] + kb + slot * 8);
      *(s8*)&As[row * 64 + ((slot ^ (row & 7)) << 3)] = v;
    }
#pragma unroll
    for (int p = 0; p < 2; ++p) {
      int row = p * 32 + (tid >> 3);
      s8 v = *(const s8*)(Wt + (size_t)(n0 + row) * K + kb + slot * 8);
      *(s8*)&Bs[row * 64 + ((slot ^ (row & 7)) << 3)] = v;
    }
    __syncthreads();
#pragma unroll
    for (int kk = 0; kk < 64; kk += 32) {
      const int sb = (kk >> 3) + lg;
      s8 af[4], bf[2];
#pragma unroll
      for (int fm = 0; fm < 4; ++fm) {
        int row = wr * 64 + fm * 16 + lr;
        af[fm] = *(const s8*)&As[row * 64 + ((sb ^ (row & 7)) << 3)];
      }
#pragma unroll
      for (int fn = 0; fn < 2; ++fn) {
        int row = wc * 32 + fn * 16 + lr;
        bf[fn] = *(const s8*)&Bs[row * 64 + ((sb ^ (row & 7)) << 3)];
      }
#pragma unroll
      for (int fm = 0; fm < 4; ++fm)
#pragma unroll
        for (int fn = 0; fn < 2; ++fn)
          acc[fm][fn] = __builtin_amdgcn_mfma_f32_16x16x32_bf16(af[fm], bf[fn], acc[fm][fn], 0, 0, 0);
    }
  }
#pragma unroll
  for (int fm = 0; fm < 4; ++fm) {
#pragma unroll
    for (int fn = 0; fn < 2; ++fn) {
      int col = n0 + wc * 32 + fn * 16 + lr;
      int rowb = m0 + wr * 64 + fm * 16 + lg * 4;
      float bv = bias[col];
#pragma unroll
      for (int j = 0; j < 4; ++j) {
        if (rowb + j >= cnt) continue;
        float v = acc[fm][fn][j] + bv;
        if (flags & 1) v = fmaxf(v, 0.f);
        if (flags & 2)
          ((float*)C_)[(size_t)e * cB + (size_t)(rowb + j) * N + col] = v;
        else
          ((__hip_bfloat16*)C_)[(size_t)e * cB + (size_t)(rowb + j) * N + col] = __float2bfloat16(v);
      }
    }
  }
}

// ---------------- attention v2: 256 thr, 2 lanes/query, score LDS, RoPE table -------
__global__ __launch_bounds__(256) void attn_k(const float* __restrict__ q,
                                              const float* __restrict__ kk,
                                              const float* __restrict__ vv,
                                              __hip_bfloat16* __restrict__ aob) {
  int b = blockIdx.x / H, h = blockIdx.x % H;
  __shared__ float ks[64][32], vs[64][32];
  __shared__ float sc[64][128];
  const int tid = threadIdx.x;
#pragma unroll
  for (int i = 0; i < 2; ++i) {
    int fi = tid + 256 * i;          // [0,512)
    int l = fi >> 3, c = (fi & 7) << 2;
    *(float4*)&ks[l][c] = *(const float4*)&kk[(size_t)(b * L + l) * E + h * HD + c];
    *(float4*)&vs[l][c] = *(const float4*)&vv[(size_t)(b * L + l) * E + h * HD + c];
  }
  __syncthreads();
  const int qrow = tid >> 1, half = tid & 1;
  const float* qp = &q[(size_t)(b * S + qrow) * E + h * HD + half * 16];
  float qv[16];
#pragma unroll
  for (int d = 0; d < 16; ++d) qv[d] = qp[d];
  const float TBL[16] = {
    1.0f, 0.5623413251903491f, 0.31622776601683794f, 0.17782794100389228f,
    0.1f, 0.05623413251903491f, 0.031622776601683794f, 0.017782794100389228f,
    0.01f, 0.005623413251903491f, 0.0031622776601683794f, 0.0017782794100389228f,
    0.001f, 0.0005623413251903491f, 0.00031622776601683794f, 0.00017782794100389228f};
#pragma unroll
  for (int dd = 0; dd < 8; ++dd) {
    float ang = (float)qrow * TBL[half * 8 + dd];
    float sn, cs;
    __sincosf(ang, &sn, &cs);
    float x1 = qv[2 * dd], x2 = qv[2 * dd + 1];
    qv[2 * dd] = x1 * cs - x2 * sn;
    qv[2 * dd + 1] = x1 * sn + x2 * cs;
  }
  const float scale = 0.17677669529663687f;  // 1/sqrt(32)
#pragma unroll
  for (int d = 0; d < 16; ++d) qv[d] *= scale;
  const int cbase = half * 16;
  float mx = -1e30f;
  for (int l = 0; l < 64; ++l) {
    float p = 0.f;
#pragma unroll
    for (int d = 0; d < 16; ++d) p += qv[d] * ks[l][cbase + d];
    p += __shfl_xor(p, 1);
    if (!half) sc[l][qrow] = p;
    mx = fmaxf(mx, p);
  }
  __syncthreads();
  float o[16];
#pragma unroll
  for (int d = 0; d < 16; ++d) o[d] = 0.f;
  float sum = 0.f;
  for (int l = 0; l < 64; ++l) {
    float wgt = __expf(sc[l][qrow] - mx);
    sum += wgt;
#pragma unroll
    for (int d = 0; d < 16; ++d) o[d] += wgt * vs[l][cbase + d];
  }
  float inv = 1.0f / sum;
  __hip_bfloat16* op = &aob[(size_t)(b * S + qrow) * E + h * HD + cbase];
#pragma unroll
  for (int d = 0; d < 16; ++d) op[d] = __float2bfloat16(o[d] * inv);
}

// ---------------- combine ----------------
__global__ __launch_bounds__(256) void combine_k(const float* __restrict__ x1,
                                                 const float* __restrict__ eoc,
                                                 const float* __restrict__ pk,
                                                 const int* __restrict__ idx,
                                                 const int* __restrict__ ppos,
                                                 float* __restrict__ out) {
  int g = blockIdx.x * 256 + threadIdx.x;  // T*E = 196608
  int t = g / E;
  int e = g - t * E;
  int i0 = idx[t * 2], i1 = idx[t * 2 + 1];
  int p0 = ppos[t * 2], p1 = ppos[t * 2 + 1];
  out[g] = x1[g] + pk[t * 2] * eoc[((size_t)i0 * T + p0) * E + e]
                 + pk[t * 2 + 1] * eoc[((size_t)i1 * T + p1) * E + e];
}

extern "C" void kernel_launch(void* const* d_in, const int* in_sizes, int n_in,
                              void* d_out, int out_size, void* d_ws, size_t ws_size,
                              hipStream_t stream) {
  const float* x    = (const float*)d_in[0];
  const float* r1w  = (const float*)d_in[1];
  const float* r2w  = (const float*)d_in[2];
  const float* latW = (const float*)d_in[3];
  const float* latb = (const float*)d_in[4];
  const float* qW   = (const float*)d_in[5];
  const float* qb   = (const float*)d_in[6];
  const float* kW   = (const float*)d_in[7];
  const float* kb   = (const float*)d_in[8];
  const float* vW   = (const float*)d_in[9];
  const float* vb   = (const float*)d_in[10];
  const float* oW   = (const float*)d_in[11];
  const float* ob   = (const float*)d_in[12];
  const float* rW   = (const float*)d_in[13];
  const float* rb   = (const float*)d_in[14];
  const float* e1W  = (const float*)d_in[15];
  const float* e1b  = (const float*)d_in[16];
  const float* swW  = (const float*)d_in[17];
  const float* swb  = (const float*)d_in[18];
  const float* e2W  = (const float*)d_in[19];
  const float* e2b  = (const float*)d_in[20];
  float* out = (float*)d_out;

  float* ws = (float*)d_ws;
  float* xn1  = ws;                                         // 196608 f32
  __hip_bfloat16* xnb   = (__hip_bfloat16*)(ws + 196608);   // 196608 bf16
  __hip_bfloat16* lat16 = (__hip_bfloat16*)(ws + 294912);   // 98304 bf16
  float* qbuf = ws + 344064;            // 196608 f32
  float* kbuf = ws + 540672;            // 98304
  float* vbuf = ws + 638976;            // 98304
  __hip_bfloat16* aob   = (__hip_bfloat16*)(ws + 737280);   // 196608 bf16
  float* x1   = ws + 835584;            // 196608
  float* pk   = ws + 1032192;           // 2048
  int*   idx  = (int*)(ws + 1034240);   // 2048
  int*   toklist = (int*)(ws + 1036288);  // 8192
  int*   ppos    = (int*)(ws + 1044480);  // 2048
  int*   cnt     = (int*)(ws + 1046528);  // 8 (pad 256)
  __hip_bfloat16* qWt = (__hip_bfloat16*)(ws + 1046784);    // 36864 bf16
  __hip_bfloat16* kWt = (__hip_bfloat16*)(ws + 1065216);
  __hip_bfloat16* vWt = (__hip_bfloat16*)(ws + 1083648);
  __hip_bfloat16* oWt = (__hip_bfloat16*)(ws + 1102080);
  __hip_bfloat16* hb    = (__hip_bfloat16*)(ws + 1120512);  // 196608 bf16
  __hip_bfloat16* e1Wt  = (__hip_bfloat16*)(ws + 1218816);  // 1179648 bf16
  __hip_bfloat16* swWt  = (__hip_bfloat16*)(ws + 1808640);  // 4718592 bf16
  __hip_bfloat16* e2Wt  = (__hip_bfloat16*)(ws + 4167936);  // 1179648 bf16
  __hip_bfloat16* t1    = (__hip_bfloat16*)(ws + 4757760);  // 6291456 bf16
  __hip_bfloat16* t2    = (__hip_bfloat16*)(ws + 7903488);  // 6291456 bf16
  float* eoc  = ws + 11049216;          // 1572864 f32
  float* part = ws + 12622080;          // 6291456 f32

  // 1) rmsnorm1 (fp32 + bf16)
  rmsnorm_bf_k<<<T, 64, 0, stream>>>(x, r1w, xn1, xnb);
  // 2) MEGA: latent partials (768 blocks) + all weight tconv backfill (7056 blocks)
  mega_k<<<7824, 256, 0, stream>>>(xn1, latW, part,
                                   e1W, swW, e2W, qW, kW, vW, oW,
                                   e1Wt, swWt, e2Wt, qWt, kWt, vWt, oWt);
  // 3) reduce partials -> lat16
  lat_reduce_k<<<(8 * LE) / 256, 256, 0, stream>>>(part, latb, lat16);
  // 4) q,k,v projections via MFMA
  qkv_mm_k<<<dim3(3, 8, 3), 256, 0, stream>>>(xnb, lat16, qWt, kWt, vWt,
                                              qb, kb, vb, qbuf, kbuf, vbuf);
  // 5) attention v2 (rope fused) -> bf16
  attn_k<<<B * H, 256, 0, stream>>>(qbuf, kbuf, vbuf, aob);
  // 6) o-proj + residual via MFMA
  oproj_mm_k<<<dim3(3, 8), 256, 0, stream>>>(aob, oWt, ob, x, x1);
  // 7) rmsnorm2 + router fused
  router_rms_k<<<T, 64, 0, stream>>>(x1, r2w, rW, rb, hb, pk, idx);
  // 8) deterministic compaction
  compact_k<<<1, 512, 0, stream>>>(idx, toklist, ppos, cnt);
  // 9) MoE top-2 stages (compact rows, early exit)
  moe_gemm_g<<<dim3(ED / 64, 8, NEXP), 256, 0, stream>>>(
      hb, e1Wt, e1b, t1, toklist, cnt, ED, E, 0, (long)ED * E, ED, (long)T * ED, 4);
  moe_gemm_g<<<dim3(ED / 64, 8, NEXP), 256, 0, stream>>>(
      t1, swWt, swb, t2, toklist, cnt, ED, ED, (long)T * ED, (long)ED * ED, ED, (long)T * ED, 1);
  moe_gemm_g<<<dim3(E / 64, 8, NEXP), 256, 0, stream>>>(
      t2, e2Wt, e2b, eoc, toklist, cnt, E, ED, (long)T * ED, (long)E * ED, E, (long)T * E, 2);
  // 10) combine
  combine_k<<<(T * E) / 256, 256, 0, stream>>>(x1, eoc, pk, idx, ppos, out);
}